// Round 10
// baseline (741.262 us; speedup 1.0000x reference)
//
#include <hip/hip_runtime.h>

#define NV 50000
#define NE 800000
#define NB 8
#define NH 128
#define NLAT 64
#define NTD 16
#define NL 4
#define SK 136   // LDS row stride (bf16 elems) for MFMA A tiles
#define SKB 136  // LDS row stride (bytes) for fp8 hid tile in k_edge
#define MTB 132  // LDS stride (bytes) for transposed fp8 m tile

typedef __attribute__((ext_vector_type(8))) short short8;
typedef __attribute__((ext_vector_type(4))) float f32x4;
typedef __attribute__((ext_vector_type(2))) float f32x2;

__device__ __forceinline__ float silu_f(float x){
    float e = __expf(-x);
    return x * __builtin_amdgcn_rcpf(1.0f + e);
}

// HW packed f32->bf16 convert (RNE)
__device__ __forceinline__ unsigned cvtpk(float a, float b){
    unsigned r;
    asm("v_cvt_pk_bf16_f32 %0, %1, %2" : "=v"(r) : "v"(a), "v"(b));
    return r;
}
__device__ __forceinline__ unsigned short f2bf_fast(float x){
    return (unsigned short)cvtpk(x, x);
}
// bit-twiddle fallback for one-shot pack kernel
__device__ __forceinline__ unsigned short f2bf(float x){
    unsigned u = __float_as_uint(x);
    unsigned r = (u >> 16) & 1;
    u += 0x7fffu + r;
    return (unsigned short)(u >> 16);
}
__device__ __forceinline__ float bflo(unsigned u){ return __uint_as_float(u << 16); }
__device__ __forceinline__ float bfhi(unsigned u){ return __uint_as_float(u & 0xffff0000u); }

// 32 bf16 (LDS, 16B aligned) -> 32 fp8 bytes at dstg (global)
__device__ __forceinline__ void bf16row_to_fp8(const unsigned short* src, unsigned char* dstg){
    unsigned ow[8];
    #pragma unroll
    for (int c = 0; c < 8; c++){
        uint2 uu = *(const uint2*)(src + c*4);
        unsigned w = __builtin_amdgcn_cvt_pk_fp8_f32(bflo(uu.x), bfhi(uu.x), 0, false);
        w = __builtin_amdgcn_cvt_pk_fp8_f32(bflo(uu.y), bfhi(uu.y), w, true);
        ow[c] = w;
    }
    uint4 o0, o1;
    o0.x = ow[0]; o0.y = ow[1]; o0.z = ow[2]; o0.w = ow[3];
    o1.x = ow[4]; o1.y = ow[5]; o1.z = ow[6]; o1.w = ow[7];
    *(uint4*)(dstg)      = o0;
    *(uint4*)(dstg + 16) = o1;
}

// 16 bf16 (LDS, 16B aligned) -> 16 fp8 bytes at dstg (global)
__device__ __forceinline__ void bf16row16_to_fp8(const unsigned short* src, unsigned char* dstg){
    unsigned ow[4];
    #pragma unroll
    for (int c = 0; c < 4; c++){
        uint2 uu = *(const uint2*)(src + c*4);
        unsigned w = __builtin_amdgcn_cvt_pk_fp8_f32(bflo(uu.x), bfhi(uu.x), 0, false);
        w = __builtin_amdgcn_cvt_pk_fp8_f32(bflo(uu.y), bfhi(uu.y), w, true);
        ow[c] = w;
    }
    uint4 o0;
    o0.x = ow[0]; o0.y = ow[1]; o0.z = ow[2]; o0.w = ow[3];
    *(uint4*)(dstg) = o0;
}

// ---------------- setup ----------------
__global__ void k_setup(const float* __restrict__ z, const float* __restrict__ t,
                        const float* __restrict__ te_w1, const float* __restrict__ te_b1,
                        const float* __restrict__ te_w2, const float* __restrict__ te_b2,
                        const float* __restrict__ cp_w, const float* __restrict__ cp_b,
                        float* __restrict__ tconst, float* __restrict__ zcp)
{
    __shared__ float hid[NTD];
    __shared__ float emb[NTD];
    int tid = threadIdx.x;
    float ts = t[0];
    if (tid < NTD) hid[tid] = silu_f(ts * te_w1[tid] + te_b1[tid]);
    __syncthreads();
    if (tid < NTD){
        float a = te_b2[tid];
        for (int j = 0; j < NTD; j++) a += hid[j] * te_w2[j*NTD + tid];
        emb[tid] = a;
    }
    __syncthreads();
    float tc = cp_b[tid];
    for (int j = 0; j < NTD; j++) tc += emb[j] * cp_w[(NLAT + j)*NH + tid];
    tconst[tid] = tc;
    for (int b = 0; b < NB; b++){
        float a = 0.f;
        for (int k = 0; k < NLAT; k++) a += z[b*NLAT + k] * cp_w[k*NH + tid];
        zcp[b*NH + tid] = a;
    }
}

// h is stored bf16: one packed dword (2 channels) per thread
__global__ void k_init(const int* __restrict__ batch, const float* __restrict__ zcp,
                       const float* __restrict__ tconst, unsigned short* __restrict__ h)
{
    int pid = blockIdx.x*256 + threadIdx.x;      // NV*64 pairs
    int v = pid >> 6, d0 = (pid & 63) * 2;
    int b = batch[v];
    float x0 = zcp[b*NH + d0]     + tconst[d0];
    float x1 = zcp[b*NH + d0 + 1] + tconst[d0 + 1];
    ((unsigned*)h)[pid] = cvtpk(x0, x1);
}

__global__ void k_xt(const float* __restrict__ pos0, const float* __restrict__ pos1,
                     const float* __restrict__ t, float* __restrict__ xt)
{
    int idx = blockIdx.x*256 + threadIdx.x;
    if (idx < NV*3){
        float ts = t[0];
        xt[idx] = (1.f - ts)*pos0[idx] + ts*pos1[idx];
    }
}

// ---------------- CSR build ----------------
__global__ void k_hist(const int* __restrict__ dst, int* __restrict__ cnt)
{
    int e = blockIdx.x*256 + threadIdx.x;
    if (e < NE) atomicAdd(&cnt[dst[e]], 1);
}

__global__ void k_scan1(const int* __restrict__ deg, int* __restrict__ bsum)
{
    __shared__ int s[256];
    int tid = threadIdx.x;
    int idx = blockIdx.x*256 + tid;
    s[tid] = (idx < NV) ? deg[idx] : 0;
    __syncthreads();
    for (int off = 128; off > 0; off >>= 1){
        if (tid < off) s[tid] += s[tid + off];
        __syncthreads();
    }
    if (tid == 0) bsum[blockIdx.x] = s[0];
}

__global__ void k_scan2(int* __restrict__ bsum)
{
    __shared__ int s[256];
    int tid = threadIdx.x;
    int v = (tid < 196) ? bsum[tid] : 0;
    s[tid] = v;
    __syncthreads();
    for (int off = 1; off < 256; off <<= 1){
        int a = s[tid];
        int b = (tid >= off) ? s[tid - off] : 0;
        __syncthreads();
        s[tid] = a + b;
        __syncthreads();
    }
    if (tid < 196) bsum[tid] = (tid == 0) ? 0 : s[tid - 1];
}

__global__ void k_scan3(const int* deg, const int* __restrict__ bsum,
                        int* __restrict__ rowptr, int* cursor)
{
    __shared__ int s[256];
    int tid = threadIdx.x;
    int idx = blockIdx.x*256 + tid;
    int v = (idx < NV) ? deg[idx] : 0;
    s[tid] = v;
    __syncthreads();
    for (int off = 1; off < 256; off <<= 1){
        int a = s[tid];
        int b = (tid >= off) ? s[tid - off] : 0;
        __syncthreads();
        s[tid] = a + b;
        __syncthreads();
    }
    int excl = bsum[blockIdx.x] + ((tid == 0) ? 0 : s[tid - 1]);
    if (idx < NV){
        rowptr[idx] = excl;
        cursor[idx] = excl;
    }
    if (idx == NV - 1) rowptr[NV] = NE;
}

__global__ void k_scatter(const int* __restrict__ dst, int* __restrict__ cursor,
                          int* __restrict__ csr_eid, int* __restrict__ csr_dst)
{
    int e = blockIdx.x*256 + threadIdx.x;
    if (e < NE){
        int i = dst[e];
        int p = atomicAdd(&cursor[i], 1);
        csr_eid[p] = e;
        csr_dst[p] = i;
    }
}

// ---------------- pack weights -> bf16 [l][{eWd,eWs,eW2,nW1d,nW1a,nW2}][n][k] ----------------
__global__ void k_pack_wpk(const float* __restrict__ ew1, const float* __restrict__ ew2,
                           const float* __restrict__ nw1, const float* __restrict__ nw2,
                           unsigned short* __restrict__ wpk)
{
    int idx = blockIdx.x*256 + threadIdx.x;
    int lm = idx >> 14;
    int l = lm / 6, m = lm % 6;
    int r = idx & 16383;
    int n = r >> 7, k = r & 127;
    float v;
    if (m < 2)       v = ew1[l*33152 + (m*128 + k)*128 + n];
    else if (m == 2) v = ew2[l*16384 + k*128 + n];
    else if (m < 5)  v = nw1[l*32768 + ((m-3)*128 + k)*128 + n];
    else             v = nw2[l*16384 + k*128 + n];
    wpk[idx] = f2bf(v);
}

// ---------------- pack W2 -> fp8 [l][n][k] ----------------
__global__ void k_pack_w2f8(const float* __restrict__ ew2, unsigned char* __restrict__ w2f8)
{
    int idx = blockIdx.x*256 + threadIdx.x;        // 4*16384
    int l = idx >> 14, r = idx & 16383;
    int n = r >> 7, k = r & 127;
    float v = ew2[l*16384 + k*128 + n];
    w2f8[idx] = (unsigned char)__builtin_amdgcn_cvt_pk_fp8_f32(v, v, 0, false);
}

// ---------------- layer-0 pre-projection (MFMA, merged branches; d->bf16, s->fp8; zeroes agg) ----------------
__global__ __launch_bounds__(256) void k_pre_mfma(
    const unsigned short* __restrict__ h, const float* __restrict__ xt,
    const unsigned short* __restrict__ wpk_l,   // Wd at +0, Ws at +16384
    const float* __restrict__ w1c, const float* __restrict__ b1,
    unsigned short* __restrict__ pre_di, unsigned char* __restrict__ pre_sj,
    float* __restrict__ agg)
{
    __shared__ __align__(16) unsigned short asd[64*SK];    // A tile; reused as d-out tile
    __shared__ __align__(16) unsigned short obuf[64*SK];   // s-out tile (bf16)
    __shared__ float xts[64*4];
    int tid = threadIdx.x;
    int tile0 = blockIdx.x*64;

    {
        int r = tid >> 2, dq = tid & 3;
        int node = tile0 + r;
        bool valid = node < NV;
        const uint4* hrow = (const uint4*)(h + (size_t)node*NH + dq*32);
        uint4 z4; z4.x = z4.y = z4.z = z4.w = 0u;
        #pragma unroll
        for (int c = 0; c < 4; c++){
            uint4 o = valid ? hrow[c] : z4;
            *(uint4*)&asd[r*SK + dq*32 + c*8] = o;
        }
        // zero agg rows for layer-0 edge pass
        if (valid){
            float4 zf = make_float4(0.f,0.f,0.f,0.f);
            float* ag = agg + (size_t)node*NH + dq*32;
            #pragma unroll
            for (int c = 0; c < 8; c++) *(float4*)(ag + c*4) = zf;
        }
    }
    if (tid < 64){
        int node = tile0 + tid;
        bool valid = node < NV;
        xts[tid*4+0] = valid ? xt[node*3+0] : 0.f;
        xts[tid*4+1] = valid ? xt[node*3+1] : 0.f;
        xts[tid*4+2] = valid ? xt[node*3+2] : 0.f;
        xts[tid*4+3] = 0.f;
    }

    int w = tid >> 6, l = tid & 63;
    int lr = l & 15, lq = l >> 4;

    short8 bfrd[2][4], bfrs[2][4];
    #pragma unroll
    for (int nt = 0; nt < 2; nt++)
        #pragma unroll
        for (int kc = 0; kc < 4; kc++){
            bfrd[nt][kc] = *(const short8*)(wpk_l +          (w*32 + nt*16 + lr)*128 + kc*32 + lq*8);
            bfrs[nt][kc] = *(const short8*)(wpk_l + 16384 +  (w*32 + nt*16 + lr)*128 + kc*32 + lq*8);
        }

    f32x4 accd[4][2], accs[4][2];
    #pragma unroll
    for (int mt = 0; mt < 4; mt++)
        #pragma unroll
        for (int nt = 0; nt < 2; nt++){
            accd[mt][nt] = (f32x4){0.f,0.f,0.f,0.f};
            accs[mt][nt] = (f32x4){0.f,0.f,0.f,0.f};
        }

    __syncthreads();

    #pragma unroll
    for (int kc = 0; kc < 4; kc++)
        #pragma unroll
        for (int mt = 0; mt < 4; mt++){
            short8 af = *(const short8*)&asd[(mt*16 + lr)*SK + kc*32 + lq*8];
            #pragma unroll
            for (int nt = 0; nt < 2; nt++){
                accd[mt][nt] = __builtin_amdgcn_mfma_f32_16x16x32_bf16(af, bfrd[nt][kc], accd[mt][nt], 0, 0, 0);
                accs[mt][nt] = __builtin_amdgcn_mfma_f32_16x16x32_bf16(af, bfrs[nt][kc], accs[mt][nt], 0, 0, 0);
            }
        }
    __syncthreads();

    #pragma unroll
    for (int nt = 0; nt < 2; nt++){
        int col = w*32 + nt*16 + lr;
        float c0 = w1c[col], c1 = w1c[128 + col], c2 = w1c[256 + col];
        float bb = b1[col];
        #pragma unroll
        for (int mt = 0; mt < 4; mt++){
            #pragma unroll
            for (int r = 0; r < 4; r++){
                int row = mt*16 + lq*4 + r;
                float qv = xts[row*4+0]*c0 + xts[row*4+1]*c1 + xts[row*4+2]*c2;
                asd [row*SK + col] = f2bf_fast(accd[mt][nt][r] + qv + bb);
                obuf[row*SK + col] = f2bf_fast(accs[mt][nt][r] - qv);
            }
        }
    }
    __syncthreads();

    {
        int r = tid >> 2, dq = tid & 3;
        int node = tile0 + r;
        if (node < NV){
            #pragma unroll
            for (int c = 0; c < 4; c++){
                uint4 vd = *(const uint4*)&asd[r*SK + dq*32 + c*8];
                *(uint4*)(pre_di + (size_t)node*NH + dq*32 + c*8) = vd;
            }
            bf16row_to_fp8(&obuf[r*SK + dq*32], pre_sj + (size_t)node*NH + dq*32);
        }
    }
}

// ---------------- fused edge kernel: 128-edge tiles; fp8; merged col passes (64 AGPR) ----------------
// silu via direct 256-entry fp8->fp8 LDS LUT (broadcast-friendly; 2-way conflicts are free).
// A-fragments are loaded from LDS ONCE and feed both column passes (acc[2][8], 64 acc regs) --
// halves ds_read_b64 count vs the 2-pass version. Regs ~112-120 -> 128-reg step, 4 waves/EU,
// so launch_bounds min-waves 4 (5 would force <=102 regs -> spill, per R8 lesson).
__global__ __launch_bounds__(256, 4) void k_edge_mfma(
    const unsigned short* __restrict__ pre_di, const unsigned char* __restrict__ pre_sj,
    const int* __restrict__ csr_eid, const int* __restrict__ csr_dst,
    const int* __restrict__ srcrow, const int* __restrict__ rowptr,
    const unsigned char* __restrict__ w2f8,   // [n][k] fp8
    const float* __restrict__ b2,
    float* __restrict__ agg)
{
    __shared__ __align__(16) unsigned char hbuf[128*SKB];   // 17.4 KB: fp8 hid tile, then m tile
    __shared__ unsigned lutS[256];                          // fp8 code -> fp8(silu(decode(code)))
    __shared__ int nid[128];
    __shared__ int flagL, flagR;
    __shared__ unsigned long long brk0_s, brk1_s;
    int tid = threadIdx.x;
    unsigned char* hids8 = hbuf;       // [128][SKB] during MFMA passes
    unsigned char* m_t   = hbuf;       // [128][MTB] after the post-MFMA barrier

    int b = blockIdx.x;
    int mapped = (b < 6248) ? ((b & 7)*781 + (b >> 3)) : b;
    int p0 = mapped * 128;

    // build the silu LUT (one exact silu per thread, once per block)
    {
        f32x2 pv = __builtin_amdgcn_cvt_pk_f32_fp8((unsigned)tid, false);
        float y = silu_f(pv.x);
        lutS[tid] = __builtin_amdgcn_cvt_pk_fp8_f32(y, y, 0, false) & 0xffu;
    }

    if (tid == 0){
        flagL = (rowptr[csr_dst[p0]] < p0) ? 1 : 0;
        flagR = (rowptr[csr_dst[p0 + 127] + 1] > p0 + 128) ? 1 : 0;
    }
    __syncthreads();   // LUT visible before hid phase

    // hid phase: di bf16 + sj fp8 -> quantize fp8 -> LUT(silu) -> fp8 LDS
    #pragma unroll
    for (int sub = 0; sub < 2; sub++){
        int el = sub*64 + (tid >> 2), q = tid & 3;
        int p = p0 + el;
        int eid = csr_eid[p];
        int iN  = csr_dst[p];
        int jN  = srcrow[eid];
        if (q == 0) nid[el] = iN;
        const uint4* gd = (const uint4*)(pre_di + (size_t)iN*NH + q*32);
        const uint4* gs = (const uint4*)(pre_sj + (size_t)jN*NH + q*32);
        uint4 s0 = gs[0], s1 = gs[1];
        unsigned sw[8] = {s0.x, s0.y, s0.z, s0.w, s1.x, s1.y, s1.z, s1.w};
        #pragma unroll
        for (int c = 0; c < 4; c++){
            uint4 a = gd[c];
            f32x2 pa = __builtin_amdgcn_cvt_pk_f32_fp8(sw[c*2],   false);
            f32x2 pb = __builtin_amdgcn_cvt_pk_f32_fp8(sw[c*2],   true);
            f32x2 pc = __builtin_amdgcn_cvt_pk_f32_fp8(sw[c*2+1], false);
            f32x2 pd = __builtin_amdgcn_cvt_pk_f32_fp8(sw[c*2+1], true);
            float x0 = bflo(a.x) + pa.x;
            float x1 = bfhi(a.x) + pa.y;
            float x2 = bflo(a.y) + pb.x;
            float x3 = bfhi(a.y) + pb.y;
            float x4 = bflo(a.z) + pc.x;
            float x5 = bfhi(a.z) + pc.y;
            float x6 = bflo(a.w) + pd.x;
            float x7 = bfhi(a.w) + pd.y;
            unsigned q0 = __builtin_amdgcn_cvt_pk_fp8_f32(x0, x1, 0, false);
            q0 = __builtin_amdgcn_cvt_pk_fp8_f32(x2, x3, q0, true);
            unsigned q1 = __builtin_amdgcn_cvt_pk_fp8_f32(x4, x5, 0, false);
            q1 = __builtin_amdgcn_cvt_pk_fp8_f32(x6, x7, q1, true);
            unsigned w0 =  lutS[q0 & 0xff]
                        | (lutS[(q0 >> 8)  & 0xff] << 8)
                        | (lutS[(q0 >> 16) & 0xff] << 16)
                        | (lutS[ q0 >> 24        ] << 24);
            unsigned w1 =  lutS[q1 & 0xff]
                        | (lutS[(q1 >> 8)  & 0xff] << 8)
                        | (lutS[(q1 >> 16) & 0xff] << 16)
                        | (lutS[ q1 >> 24        ] << 24);
            uint2 o; o.x = w0; o.y = w1;
            *(uint2*)&hids8[el*SKB + q*32 + c*8] = o;
        }
    }

    int w = tid >> 6, l = tid & 63;
    int lr = l & 15, lq = l >> 4;
    // B frags for both col passes: pass p covers cols p*64 + w*16 + lr
    long bfr[2][4];
    #pragma unroll
    for (int pass = 0; pass < 2; pass++)
        #pragma unroll
        for (int kc = 0; kc < 4; kc++)
            bfr[pass][kc] = *(const long*)(w2f8 + (pass*64 + w*16 + lr)*128 + kc*32 + lq*8);

    __syncthreads();

    if (tid < 64){
        bool bb = (tid > 0) && (nid[tid] != nid[tid - 1]);
        unsigned long long mask = __ballot(bb);
        if (tid == 0) brk0_s = mask;
    } else if (tid < 128){
        int lane = tid - 64;
        bool bb = (nid[64 + lane] != nid[63 + lane]);
        unsigned long long mask = __ballot(bb);
        if (lane == 0) brk1_s = mask;
    }

    // merged MFMA: each A-frag loaded once, feeds both column passes
    f32x4 acc[2][8];
    #pragma unroll
    for (int pass = 0; pass < 2; pass++)
        #pragma unroll
        for (int mt = 0; mt < 8; mt++) acc[pass][mt] = (f32x4){0.f,0.f,0.f,0.f};
    #pragma unroll
    for (int kc = 0; kc < 4; kc++){
        #pragma unroll
        for (int mt = 0; mt < 8; mt++){
            long af = *(const long*)&hids8[(mt*16 + lr)*SKB + kc*32 + lq*8];
            acc[0][mt] = __builtin_amdgcn_mfma_f32_16x16x32_fp8_fp8(af, bfr[0][kc], acc[0][mt], 0, 0, 0);
            acc[1][mt] = __builtin_amdgcn_mfma_f32_16x16x32_fp8_fp8(af, bfr[1][kc], acc[1][mt], 0, 0, 0);
        }
    }

    unsigned mreg[2][8];
    #pragma unroll
    for (int pass = 0; pass < 2; pass++){
        int col = pass*64 + w*16 + lr;
        float bv = b2[col];
        #pragma unroll
        for (int mt = 0; mt < 8; mt++){
            unsigned qv = __builtin_amdgcn_cvt_pk_fp8_f32(acc[pass][mt][0] + bv, acc[pass][mt][1] + bv, 0, false);
            qv = __builtin_amdgcn_cvt_pk_fp8_f32(acc[pass][mt][2] + bv, acc[pass][mt][3] + bv, qv, true);
            mreg[pass][mt] =  lutS[qv & 0xff]
                           | (lutS[(qv >> 8)  & 0xff] << 8)
                           | (lutS[(qv >> 16) & 0xff] << 16)
                           | (lutS[ qv >> 24        ] << 24);
        }
    }
    __syncthreads();   // all hids8 reads complete -> region reusable as m tile

    #pragma unroll
    for (int pass = 0; pass < 2; pass++){
        int col = pass*64 + w*16 + lr;
        #pragma unroll
        for (int mt = 0; mt < 8; mt++)
            *(unsigned*)&m_t[col*MTB + mt*16 + lq*4] = mreg[pass][mt];
    }
    __syncthreads();

    {
        int half = tid >> 7, d = tid & 127;
        int r0 = half * 64;
        bool junc = !((brk1_s) & 1ull);
        unsigned long long m2 = half ? (brk1_s & ~1ull) : brk0_s;
        bool leftCont  = half ? junc : (flagL != 0);
        bool rightCont = half ? (flagR != 0) : junc;

        float run = 0.f;
        int curn = nid[r0];
        bool firstRun = true;
        const unsigned char* mrow = m_t + d*MTB;

        #pragma unroll
        for (int g = 0; g < 16; g++){
            int row = r0 + g*4;
            unsigned v = *(const unsigned*)&mrow[row];
            f32x2 pa = __builtin_amdgcn_cvt_pk_f32_fp8(v, false);
            f32x2 pb = __builtin_amdgcn_cvt_pk_f32_fp8(v, true);
            float f0 = pa.x, f1 = pa.y, f2 = pb.x, f3 = pb.y;
            unsigned gm = (unsigned)((m2 >> (g*4)) & 0xFull);
            if (gm == 0u){
                run += (f0 + f1) + (f2 + f3);
            } else {
                float fv[4] = {f0, f1, f2, f3};
                #pragma unroll
                for (int r = 0; r < 4; r++){
                    if (gm & (1u << r)){
                        bool at = firstRun && leftCont;
                        if (at) atomicAdd(&agg[(size_t)curn*NH + d], run);
                        else    agg[(size_t)curn*NH + d] = run;
                        firstRun = false;
                        run = 0.f;
                        curn = nid[row + r];
                    }
                    run += fv[r];
                }
            }
        }
        bool at = (firstRun && leftCont) || rightCont;
        if (at) atomicAdd(&agg[(size_t)curn*NH + d], run);
        else    agg[(size_t)curn*NH + d] = run;
    }
}

// ---------------- fused node kernel: LN(h + MLP([h|agg])) then next-layer pre; re-zeroes agg ----------------
// 32-node tiles (grid 1563): node kernel was grid-limited at 782 blocks (~3 blocks/CU).
// h is bf16 in global memory; residual comes from the a1 LDS tile (no mid-kernel h re-read).
__global__ __launch_bounds__(256) void k_node_fused(
    unsigned short* __restrict__ h, float* __restrict__ agg,
    const unsigned short* __restrict__ wn,   // node weights: W1d, W1a, W2
    const float* __restrict__ b1, const float* __restrict__ b2,
    const float* __restrict__ g, const float* __restrict__ bta,
    const float* __restrict__ xt,
    const unsigned short* __restrict__ wpk_next,   // next-layer eWd at +0, eWs at +16384
    const float* __restrict__ w1c_next, const float* __restrict__ b1_next,
    unsigned short* __restrict__ pre_di, unsigned char* __restrict__ pre_sj,
    int do_pre)
{
    __shared__ __align__(16) unsigned short abuf[2*32*SK];
    __shared__ float ps[32][8], pq[32][8];
    __shared__ float mu_s[32], rs_s[32];
    __shared__ float xts[32*4];
    int tid = threadIdx.x;
    int tile0 = blockIdx.x*32;
    unsigned short* a1 = abuf;            // holds bf16(h) until the LN phases complete
    unsigned short* a2 = abuf + 32*SK;    // agg -> silu(mlp1) -> mlp2+b2

    {
        int r = tid >> 3, t8 = tid & 7;   // 8 threads/row, 16 channels each
        int node = tile0 + r;
        bool valid = node < NV;
        const uint4*   hrow = (const uint4*)(h   + (size_t)node*NH + t8*16);
        const float4*  arow = (const float4*)(agg + (size_t)node*NH + t8*16);
        uint4 z4; z4.x = z4.y = z4.z = z4.w = 0u;
        #pragma unroll
        for (int c = 0; c < 2; c++){
            uint4 o = valid ? hrow[c] : z4;
            *(uint4*)&a1[r*SK + t8*16 + c*8] = o;
            float4 u0 = valid ? arow[c*2]     : make_float4(0.f,0.f,0.f,0.f);
            float4 u1 = valid ? arow[c*2 + 1] : make_float4(0.f,0.f,0.f,0.f);
            uint4 p;
            p.x = cvtpk(u0.x, u0.y); p.y = cvtpk(u0.z, u0.w);
            p.z = cvtpk(u1.x, u1.y); p.w = cvtpk(u1.z, u1.w);
            *(uint4*)&a2[r*SK + t8*16 + c*8] = p;
        }
        // re-zero agg for the next layer's edge pass (only if one follows)
        if (do_pre && valid){
            float4 zf = make_float4(0.f,0.f,0.f,0.f);
            float* ag = agg + (size_t)node*NH + t8*16;
            #pragma unroll
            for (int c = 0; c < 4; c++) *(float4*)(ag + c*4) = zf;
        }
    }
    if (tid < 32){
        int node = tile0 + tid;
        bool valid = node < NV;
        xts[tid*4+0] = valid ? xt[node*3+0] : 0.f;
        xts[tid*4+1] = valid ? xt[node*3+1] : 0.f;
        xts[tid*4+2] = valid ? xt[node*3+2] : 0.f;
        xts[tid*4+3] = 0.f;
    }

    int w = tid >> 6, l = tid & 63;
    int lr = l & 15, lq = l >> 4;
    int colb = w*32;

    __syncthreads();

    f32x4 acc[2][2];
    #pragma unroll
    for (int mt = 0; mt < 2; mt++)
        #pragma unroll
        for (int nt = 0; nt < 2; nt++) acc[mt][nt] = (f32x4){0.f,0.f,0.f,0.f};

    {
        short8 bfr[2][4];
        #pragma unroll
        for (int nt = 0; nt < 2; nt++)
            #pragma unroll
            for (int kc = 0; kc < 4; kc++)
                bfr[nt][kc] = *(const short8*)(wn + (colb + nt*16 + lr)*128 + kc*32 + lq*8);
        #pragma unroll
        for (int kc = 0; kc < 4; kc++)
            #pragma unroll
            for (int mt = 0; mt < 2; mt++){
                short8 af = *(const short8*)&a1[(mt*16 + lr)*SK + kc*32 + lq*8];
                #pragma unroll
                for (int nt = 0; nt < 2; nt++)
                    acc[mt][nt] = __builtin_amdgcn_mfma_f32_16x16x32_bf16(af, bfr[nt][kc], acc[mt][nt], 0, 0, 0);
            }
    }
    {
        short8 bfr[2][4];
        #pragma unroll
        for (int nt = 0; nt < 2; nt++)
            #pragma unroll
            for (int kc = 0; kc < 4; kc++)
                bfr[nt][kc] = *(const short8*)(wn + 16384 + (colb + nt*16 + lr)*128 + kc*32 + lq*8);
        #pragma unroll
        for (int kc = 0; kc < 4; kc++)
            #pragma unroll
            for (int mt = 0; mt < 2; mt++){
                short8 af = *(const short8*)&a2[(mt*16 + lr)*SK + kc*32 + lq*8];
                #pragma unroll
                for (int nt = 0; nt < 2; nt++)
                    acc[mt][nt] = __builtin_amdgcn_mfma_f32_16x16x32_bf16(af, bfr[nt][kc], acc[mt][nt], 0, 0, 0);
            }
    }
    __syncthreads();

    // silu(mlp1) -> a2 (keeps a1 = bf16(h) intact for the residual)
    #pragma unroll
    for (int nt = 0; nt < 2; nt++){
        int col = colb + nt*16 + lr;
        float bv = b1[col];
        #pragma unroll
        for (int mt = 0; mt < 2; mt++)
            #pragma unroll
            for (int r = 0; r < 4; r++){
                int row = mt*16 + lq*4 + r;
                a2[row*SK + col] = f2bf_fast(silu_f(acc[mt][nt][r] + bv));
            }
    }
    __syncthreads();

    f32x4 acc2[2][2];
    #pragma unroll
    for (int mt = 0; mt < 2; mt++)
        #pragma unroll
        for (int nt = 0; nt < 2; nt++) acc2[mt][nt] = (f32x4){0.f,0.f,0.f,0.f};
    {
        short8 bfr[2][4];
        #pragma unroll
        for (int nt = 0; nt < 2; nt++)
            #pragma unroll
            for (int kc = 0; kc < 4; kc++)
                bfr[nt][kc] = *(const short8*)(wn + 2*16384 + (colb + nt*16 + lr)*128 + kc*32 + lq*8);
        #pragma unroll
        for (int kc = 0; kc < 4; kc++)
            #pragma unroll
            for (int mt = 0; mt < 2; mt++){
                short8 af = *(const short8*)&a2[(mt*16 + lr)*SK + kc*32 + lq*8];
                #pragma unroll
                for (int nt = 0; nt < 2; nt++)
                    acc2[mt][nt] = __builtin_amdgcn_mfma_f32_16x16x32_bf16(af, bfr[nt][kc], acc2[mt][nt], 0, 0, 0);
            }
    }
    __syncthreads();

    // mlp2 + b2 -> a2 (bf16); residual x = a1 + a2 read in the LN phases
    #pragma unroll
    for (int nt = 0; nt < 2; nt++){
        int col = colb + nt*16 + lr;
        float bv = b2[col];
        #pragma unroll
        for (int mt = 0; mt < 2; mt++)
            #pragma unroll
            for (int r = 0; r < 4; r++){
                int row = mt*16 + lq*4 + r;
                a2[row*SK + col] = f2bf_fast(acc2[mt][nt][r] + bv);
            }
    }
    __syncthreads();

    {
        int r = tid >> 3, part = tid & 7;
        float s = 0.f, q = 0.f;
        #pragma unroll
        for (int c = 0; c < 2; c++){
            uint4 ua = *(const uint4*)&a1[r*SK + part*16 + c*8];
            uint4 ub = *(const uint4*)&a2[r*SK + part*16 + c*8];
            unsigned wa[4] = {ua.x, ua.y, ua.z, ua.w};
            unsigned wb[4] = {ub.x, ub.y, ub.z, ub.w};
            #pragma unroll
            for (int k = 0; k < 4; k++){
                float x0 = bflo(wa[k]) + bflo(wb[k]);
                float x1 = bfhi(wa[k]) + bfhi(wb[k]);
                s += x0 + x1;
                q += x0*x0 + x1*x1;
            }
        }
        ps[r][part] = s; pq[r][part] = q;
    }
    __syncthreads();
    if (tid < 32){
        float s = ps[tid][0] + ps[tid][1] + ps[tid][2] + ps[tid][3]
                + ps[tid][4] + ps[tid][5] + ps[tid][6] + ps[tid][7];
        float q = pq[tid][0] + pq[tid][1] + pq[tid][2] + pq[tid][3]
                + pq[tid][4] + pq[tid][5] + pq[tid][6] + pq[tid][7];
        float mu = s * (1.f/128.f);
        float var = q * (1.f/128.f) - mu*mu;
        mu_s[tid] = mu;
        rs_s[tid] = rsqrtf(var + 1e-5f);
    }
    __syncthreads();

    uint4 opk[2];   // LN output, bf16-packed (8 channels per uint4)
    {
        int r = tid >> 3, part = tid & 7;
        int node = tile0 + r;
        float mu = mu_s[r], rs = rs_s[r];
        #pragma unroll
        for (int c = 0; c < 2; c++){
            int d = part*16 + c*8;
            uint4 ua = *(const uint4*)&a1[r*SK + d];
            uint4 ub = *(const uint4*)&a2[r*SK + d];
            unsigned wa[4] = {ua.x, ua.y, ua.z, ua.w};
            unsigned wb[4] = {ub.x, ub.y, ub.z, ub.w};
            float xv[8];
            #pragma unroll
            for (int k = 0; k < 4; k++){
                xv[2*k]   = bflo(wa[k]) + bflo(wb[k]);
                xv[2*k+1] = bfhi(wa[k]) + bfhi(wb[k]);
            }
            float o0 = g[d+0]*(xv[0] - mu)*rs + bta[d+0];
            float o1 = g[d+1]*(xv[1] - mu)*rs + bta[d+1];
            float o2 = g[d+2]*(xv[2] - mu)*rs + bta[d+2];
            float o3 = g[d+3]*(xv[3] - mu)*rs + bta[d+3];
            float o4 = g[d+4]*(xv[4] - mu)*rs + bta[d+4];
            float o5 = g[d+5]*(xv[5] - mu)*rs + bta[d+5];
            float o6 = g[d+6]*(xv[6] - mu)*rs + bta[d+6];
            float o7 = g[d+7]*(xv[7] - mu)*rs + bta[d+7];
            uint4 po;
            po.x = cvtpk(o0, o1); po.y = cvtpk(o2, o3);
            po.z = cvtpk(o4, o5); po.w = cvtpk(o6, o7);
            opk[c] = po;
            if (node < NV) *(uint4*)(h + (size_t)node*NH + d) = po;
        }
    }

    if (!do_pre) return;

    __syncthreads();   // all a1/a2 LN reads done -> abuf reusable
    // pack LN result -> a1 (bf16 A-tile)
    {
        int r = tid >> 3, part = tid & 7;
        #pragma unroll
        for (int c = 0; c < 2; c++)
            *(uint4*)&a1[r*SK + part*16 + c*8] = opk[c];
    }

    // B frags for both branches
    short8 bfrd[2][4], bfrs[2][4];
    #pragma unroll
    for (int nt = 0; nt < 2; nt++)
        #pragma unroll
        for (int kc = 0; kc < 4; kc++){
            bfrd[nt][kc] = *(const short8*)(wpk_next +         (colb + nt*16 + lr)*128 + kc*32 + lq*8);
            bfrs[nt][kc] = *(const short8*)(wpk_next + 16384 + (colb + nt*16 + lr)*128 + kc*32 + lq*8);
        }

    f32x4 accd[2][2], accs[2][2];
    #pragma unroll
    for (int mt = 0; mt < 2; mt++)
        #pragma unroll
        for (int nt = 0; nt < 2; nt++){
            accd[mt][nt] = (f32x4){0.f,0.f,0.f,0.f};
            accs[mt][nt] = (f32x4){0.f,0.f,0.f,0.f};
        }

    __syncthreads();

    #pragma unroll
    for (int kc = 0; kc < 4; kc++)
        #pragma unroll
        for (int mt = 0; mt < 2; mt++){
            short8 af = *(const short8*)&a1[(mt*16 + lr)*SK + kc*32 + lq*8];
            #pragma unroll
            for (int nt = 0; nt < 2; nt++){
                accd[mt][nt] = __builtin_amdgcn_mfma_f32_16x16x32_bf16(af, bfrd[nt][kc], accd[mt][nt], 0, 0, 0);
                accs[mt][nt] = __builtin_amdgcn_mfma_f32_16x16x32_bf16(af, bfrs[nt][kc], accs[mt][nt], 0, 0, 0);
            }
        }

    // epilogue d -> a2
    #pragma unroll
    for (int nt = 0; nt < 2; nt++){
        int col = colb + nt*16 + lr;
        float c0 = w1c_next[col], c1 = w1c_next[128 + col], c2 = w1c_next[256 + col];
        float bb = b1_next[col];
        #pragma unroll
        for (int mt = 0; mt < 2; mt++)
            #pragma unroll
            for (int r = 0; r < 4; r++){
                int row = mt*16 + lq*4 + r;
                float qv = xts[row*4+0]*c0 + xts[row*4+1]*c1 + xts[row*4+2]*c2;
                a2[row*SK + col] = f2bf_fast(accd[mt][nt][r] + qv + bb);
            }
    }
    __syncthreads();   // d-tile visible; all a1 GEMM reads complete

    // store d from a2; epilogue s -> a1
    {
        int r = tid >> 3, t8 = tid & 7;
        int node = tile0 + r;
        if (node < NV){
            #pragma unroll
            for (int c = 0; c < 2; c++){
                uint4 vv = *(const uint4*)&a2[r*SK + t8*16 + c*8];
                *(uint4*)(pre_di + (size_t)node*NH + t8*16 + c*8) = vv;
            }
        }
    }
    #pragma unroll
    for (int nt = 0; nt < 2; nt++){
        int col = colb + nt*16 + lr;
        float c0 = w1c_next[col], c1 = w1c_next[128 + col], c2 = w1c_next[256 + col];
        #pragma unroll
        for (int mt = 0; mt < 2; mt++)
            #pragma unroll
            for (int r = 0; r < 4; r++){
                int row = mt*16 + lq*4 + r;
                float qv = xts[row*4+0]*c0 + xts[row*4+1]*c1 + xts[row*4+2]*c2;
                a1[row*SK + col] = f2bf_fast(accs[mt][nt][r] - qv);
            }
    }
    __syncthreads();

    // store s from a1 (fp8 convert)
    {
        int r = tid >> 3, t8 = tid & 7;
        int node = tile0 + r;
        if (node < NV){
            bf16row16_to_fp8(&a1[r*SK + t8*16], pre_sj + (size_t)node*NH + t8*16);
        }
    }
}

// ---------------- output projection + MSE (two-stage); h is bf16 ----------------
__global__ __launch_bounds__(256) void k_out(const unsigned short* __restrict__ h,
                                             const float* __restrict__ opw, const float* __restrict__ opb,
                                             const float* __restrict__ pos0, const float* __restrict__ pos1,
                                             float* __restrict__ partial)
{
    int v = blockIdx.x*256 + threadIdx.x;
    float sse = 0.f;
    if (v < NV){
        float v0 = opb[0], v1 = opb[1], v2 = opb[2];
        const unsigned short* hr = h + (size_t)v*NH;
        for (int k = 0; k < 128; k += 8){
            uint4 hv = *(const uint4*)(hr + k);
            unsigned u[4] = {hv.x, hv.y, hv.z, hv.w};
            #pragma unroll
            for (int j = 0; j < 4; j++){
                float f0 = bflo(u[j]), f1 = bfhi(u[j]);
                int kk = k + j*2;
                v0 += f0*opw[kk*3+0] + f1*opw[(kk+1)*3+0];
                v1 += f0*opw[kk*3+1] + f1*opw[(kk+1)*3+1];
                v2 += f0*opw[kk*3+2] + f1*opw[(kk+1)*3+2];
            }
        }
        float d0 = v0 - (pos1[v*3+0] - pos0[v*3+0]);
        float d1 = v1 - (pos1[v*3+1] - pos0[v*3+1]);
        float d2 = v2 - (pos1[v*3+2] - pos0[v*3+2]);
        sse = d0*d0 + d1*d1 + d2*d2;
    }
    for (int off = 32; off > 0; off >>= 1) sse += __shfl_down(sse, off, 64);
    __shared__ float red[4];
    if ((threadIdx.x & 63) == 0) red[threadIdx.x >> 6] = sse;
    __syncthreads();
    if (threadIdx.x == 0)
        partial[blockIdx.x] = red[0] + red[1] + red[2] + red[3];
}

__global__ void k_out2(const float* __restrict__ partial, float* __restrict__ out, int nparts)
{
    int tid = threadIdx.x;
    float s = (tid < nparts) ? partial[tid] : 0.f;
    for (int off = 32; off > 0; off >>= 1) s += __shfl_down(s, off, 64);
    __shared__ float red[4];
    if ((tid & 63) == 0) red[tid >> 6] = s;
    __syncthreads();
    if (tid == 0)
        out[0] = (red[0] + red[1] + red[2] + red[3]) * (1.0f/150000.0f);
}

extern "C" void kernel_launch(void* const* d_in, const int* in_sizes, int n_in,
                              void* d_out, int out_size, void* d_ws, size_t ws_size,
                              hipStream_t stream)
{
    const float* pos0  = (const float*)d_in[0];
    const float* pos1  = (const float*)d_in[1];
    const float* z     = (const float*)d_in[2];
    const float* t     = (const float*)d_in[3];
    const int*   ei    = (const int*)d_in[4];
    const int*   batch = (const int*)d_in[5];
    const float* te_w1 = (const float*)d_in[6];
    const float* te_b1 = (const float*)d_in[7];
    const float* te_w2 = (const float*)d_in[8];
    const float* te_b2 = (const float*)d_in[9];
    const float* cp_w  = (const float*)d_in[10];
    const float* cp_b  = (const float*)d_in[11];
    const float* ew1   = (const float*)d_in[12];
    const float* eb1   = (const float*)d_in[13];
    const float* ew2   = (const float*)d_in[14];
    const float* eb2   = (const float*)d_in[15];
    const float* nw1   = (const float*)d_in[16];
    const float* nb1   = (const float*)d_in[17];
    const float* nw2   = (const float*)d_in[18];
    const float* nb2   = (const float*)d_in[19];
    const float* ln_g  = (const float*)d_in[20];
    const float* ln_b  = (const float*)d_in[21];
    const float* op_w  = (const float*)d_in[22];
    const float* op_b  = (const float*)d_in[23];

    float* ws     = (float*)d_ws;
    float* tconst = ws;                        // 128
    float* zcp    = ws + 128;                  // 1024
    float* xt     = ws + 1152;                 // 150016 (NV*3 padded)
    unsigned short* h = (unsigned short*)(ws + 151168);   // NV*NH bf16 (in old fp32 slot)
    float* agg    = ws + 151168 + (size_t)NV*NH;          // NV*NH fp32 (same address as before)
    int*   ibase  = (int*)(agg + (size_t)NV*NH);
    int*   rowptr  = ibase;                    // 50016
    int*   cursor  = ibase + 50016;            // 50016
    int*   csr_eid = ibase + 100032;           // NE
    int*   csr_dst = csr_eid + NE;             // NE
    unsigned short* pre_di = (unsigned short*)(csr_dst + NE);   // NV*NH bf16
    unsigned char*  pre_sj = (unsigned char*)(pre_di + (size_t)NV*NH); // NV*NH fp8
    unsigned short* wpk    = (unsigned short*)(pre_sj + (size_t)NV*NH); // 4*6*16384 bf16
    int*   bsum   = (int*)(wpk + 4*6*16384);                    // 256 ints
    unsigned char* w2f8 = (unsigned char*)(bsum + 256);         // 4*16384 fp8
    float* outpart = (float*)(w2f8 + 4*16384);                  // 256 floats

    const int* srcrow = ei;        // edge_index[0] = src j
    const int* dstrow = ei + NE;   // edge_index[1] = dst i

    hipMemsetAsync(cursor, 0, (size_t)NV*4, stream);
    k_setup<<<1, 128, 0, stream>>>(z, t, te_w1, te_b1, te_w2, te_b2, cp_w, cp_b, tconst, zcp);
    k_init<<<(NV*64)/256, 256, 0, stream>>>(batch, zcp, tconst, h);
    k_xt<<<(NV*3 + 255)/256, 256, 0, stream>>>(pos0, pos1, t, xt);
    k_hist<<<NE/256, 256, 0, stream>>>(dstrow, cursor);
    k_scan1<<<196, 256, 0, stream>>>(cursor, bsum);
    k_scan2<<<1, 256, 0, stream>>>(bsum);
    k_scan3<<<196, 256, 0, stream>>>(cursor, bsum, rowptr, cursor);
    k_scatter<<<NE/256, 256, 0, stream>>>(dstrow, cursor, csr_eid, csr_dst);
    k_pack_wpk<<<(4*6*16384)/256, 256, 0, stream>>>(ew1, ew2, nw1, nw2, wpk);
    k_pack_w2f8<<<(4*16384)/256, 256, 0, stream>>>(ew2, w2f8);

    for (int l = 0; l < NL; l++){
        const unsigned short* wpk_l = wpk + (size_t)l*6*16384;
        if (l == 0){
            k_pre_mfma<<<(NV + 63)/64, 256, 0, stream>>>(h, xt, wpk_l,
                                                         ew1 + 256*128, eb1,
                                                         pre_di, pre_sj, agg);
        }
        k_edge_mfma<<<NE/128, 256, 0, stream>>>(pre_di, pre_sj, csr_eid, csr_dst, srcrow, rowptr,
                                                w2f8 + (size_t)l*16384, eb2 + l*128, agg);
        int ln = (l + 1) % NL;
        const unsigned short* wpk_n = wpk + (size_t)ln*6*16384;
        const float* ew1n = ew1 + (size_t)ln*259*128;
        k_node_fused<<<(NV + 31)/32, 256, 0, stream>>>(h, agg, wpk_l + 3*16384,
                                                       nb1 + l*128, nb2 + l*128,
                                                       ln_g + l*128, ln_b + l*128,
                                                       xt, wpk_n, ew1n + 256*128, eb1 + ln*128,
                                                       pre_di, pre_sj, (l < NL-1) ? 1 : 0);
    }

    int nparts = (NV + 255)/256;   // 196
    k_out<<<nparts, 256, 0, stream>>>(h, op_w, op_b, pos0, pos1, outpart);
    k_out2<<<1, 256, 0, stream>>>(outpart, (float*)d_out, nparts);
}

// Round 11
// 716.757 us; speedup vs baseline: 1.0342x; 1.0342x over previous
//
#include <hip/hip_runtime.h>

#define NV 50000
#define NE 800000
#define NB 8
#define NH 128
#define NLAT 64
#define NTD 16
#define NL 4
#define SK 136   // LDS row stride (bf16 elems) for MFMA A tiles
#define SKB 136  // LDS row stride (bytes) for fp8 hid tile in k_edge
#define MTB 132  // LDS stride (bytes) for transposed fp8 m tile

typedef __attribute__((ext_vector_type(8))) short short8;
typedef __attribute__((ext_vector_type(4))) float f32x4;
typedef __attribute__((ext_vector_type(2))) float f32x2;

__device__ __forceinline__ float silu_f(float x){
    float e = __expf(-x);
    return x * __builtin_amdgcn_rcpf(1.0f + e);
}

// HW packed f32->bf16 convert (RNE)
__device__ __forceinline__ unsigned cvtpk(float a, float b){
    unsigned r;
    asm("v_cvt_pk_bf16_f32 %0, %1, %2" : "=v"(r) : "v"(a), "v"(b));
    return r;
}
__device__ __forceinline__ unsigned short f2bf_fast(float x){
    return (unsigned short)cvtpk(x, x);
}
// bit-twiddle fallback for one-shot pack kernel
__device__ __forceinline__ unsigned short f2bf(float x){
    unsigned u = __float_as_uint(x);
    unsigned r = (u >> 16) & 1;
    u += 0x7fffu + r;
    return (unsigned short)(u >> 16);
}
__device__ __forceinline__ float bflo(unsigned u){ return __uint_as_float(u << 16); }
__device__ __forceinline__ float bfhi(unsigned u){ return __uint_as_float(u & 0xffff0000u); }

// 32 bf16 (LDS, 16B aligned) -> 32 fp8 bytes at dstg (global)
__device__ __forceinline__ void bf16row_to_fp8(const unsigned short* src, unsigned char* dstg){
    unsigned ow[8];
    #pragma unroll
    for (int c = 0; c < 8; c++){
        uint2 uu = *(const uint2*)(src + c*4);
        unsigned w = __builtin_amdgcn_cvt_pk_fp8_f32(bflo(uu.x), bfhi(uu.x), 0, false);
        w = __builtin_amdgcn_cvt_pk_fp8_f32(bflo(uu.y), bfhi(uu.y), w, true);
        ow[c] = w;
    }
    uint4 o0, o1;
    o0.x = ow[0]; o0.y = ow[1]; o0.z = ow[2]; o0.w = ow[3];
    o1.x = ow[4]; o1.y = ow[5]; o1.z = ow[6]; o1.w = ow[7];
    *(uint4*)(dstg)      = o0;
    *(uint4*)(dstg + 16) = o1;
}

// 16 bf16 (LDS, 16B aligned) -> 16 fp8 bytes at dstg (global)
__device__ __forceinline__ void bf16row16_to_fp8(const unsigned short* src, unsigned char* dstg){
    unsigned ow[4];
    #pragma unroll
    for (int c = 0; c < 4; c++){
        uint2 uu = *(const uint2*)(src + c*4);
        unsigned w = __builtin_amdgcn_cvt_pk_fp8_f32(bflo(uu.x), bfhi(uu.x), 0, false);
        w = __builtin_amdgcn_cvt_pk_fp8_f32(bflo(uu.y), bfhi(uu.y), w, true);
        ow[c] = w;
    }
    uint4 o0;
    o0.x = ow[0]; o0.y = ow[1]; o0.z = ow[2]; o0.w = ow[3];
    *(uint4*)(dstg) = o0;
}

// ---------------- setup ----------------
__global__ void k_setup(const float* __restrict__ z, const float* __restrict__ t,
                        const float* __restrict__ te_w1, const float* __restrict__ te_b1,
                        const float* __restrict__ te_w2, const float* __restrict__ te_b2,
                        const float* __restrict__ cp_w, const float* __restrict__ cp_b,
                        float* __restrict__ tconst, float* __restrict__ zcp)
{
    __shared__ float hid[NTD];
    __shared__ float emb[NTD];
    int tid = threadIdx.x;
    float ts = t[0];
    if (tid < NTD) hid[tid] = silu_f(ts * te_w1[tid] + te_b1[tid]);
    __syncthreads();
    if (tid < NTD){
        float a = te_b2[tid];
        for (int j = 0; j < NTD; j++) a += hid[j] * te_w2[j*NTD + tid];
        emb[tid] = a;
    }
    __syncthreads();
    float tc = cp_b[tid];
    for (int j = 0; j < NTD; j++) tc += emb[j] * cp_w[(NLAT + j)*NH + tid];
    tconst[tid] = tc;
    for (int b = 0; b < NB; b++){
        float a = 0.f;
        for (int k = 0; k < NLAT; k++) a += z[b*NLAT + k] * cp_w[k*NH + tid];
        zcp[b*NH + tid] = a;
    }
}

// h is stored bf16: one packed dword (2 channels) per thread
__global__ void k_init(const int* __restrict__ batch, const float* __restrict__ zcp,
                       const float* __restrict__ tconst, unsigned short* __restrict__ h)
{
    int pid = blockIdx.x*256 + threadIdx.x;      // NV*64 pairs
    int v = pid >> 6, d0 = (pid & 63) * 2;
    int b = batch[v];
    float x0 = zcp[b*NH + d0]     + tconst[d0];
    float x1 = zcp[b*NH + d0 + 1] + tconst[d0 + 1];
    ((unsigned*)h)[pid] = cvtpk(x0, x1);
}

__global__ void k_xt(const float* __restrict__ pos0, const float* __restrict__ pos1,
                     const float* __restrict__ t, float* __restrict__ xt)
{
    int idx = blockIdx.x*256 + threadIdx.x;
    if (idx < NV*3){
        float ts = t[0];
        xt[idx] = (1.f - ts)*pos0[idx] + ts*pos1[idx];
    }
}

// ---------------- CSR build ----------------
__global__ void k_hist(const int* __restrict__ dst, int* __restrict__ cnt)
{
    int e = blockIdx.x*256 + threadIdx.x;
    if (e < NE) atomicAdd(&cnt[dst[e]], 1);
}

__global__ void k_scan1(const int* __restrict__ deg, int* __restrict__ bsum)
{
    __shared__ int s[256];
    int tid = threadIdx.x;
    int idx = blockIdx.x*256 + tid;
    s[tid] = (idx < NV) ? deg[idx] : 0;
    __syncthreads();
    for (int off = 128; off > 0; off >>= 1){
        if (tid < off) s[tid] += s[tid + off];
        __syncthreads();
    }
    if (tid == 0) bsum[blockIdx.x] = s[0];
}

__global__ void k_scan2(int* __restrict__ bsum)
{
    __shared__ int s[256];
    int tid = threadIdx.x;
    int v = (tid < 196) ? bsum[tid] : 0;
    s[tid] = v;
    __syncthreads();
    for (int off = 1; off < 256; off <<= 1){
        int a = s[tid];
        int b = (tid >= off) ? s[tid - off] : 0;
        __syncthreads();
        s[tid] = a + b;
        __syncthreads();
    }
    if (tid < 196) bsum[tid] = (tid == 0) ? 0 : s[tid - 1];
}

__global__ void k_scan3(const int* deg, const int* __restrict__ bsum,
                        int* __restrict__ rowptr, int* cursor)
{
    __shared__ int s[256];
    int tid = threadIdx.x;
    int idx = blockIdx.x*256 + tid;
    int v = (idx < NV) ? deg[idx] : 0;
    s[tid] = v;
    __syncthreads();
    for (int off = 1; off < 256; off <<= 1){
        int a = s[tid];
        int b = (tid >= off) ? s[tid - off] : 0;
        __syncthreads();
        s[tid] = a + b;
        __syncthreads();
    }
    int excl = bsum[blockIdx.x] + ((tid == 0) ? 0 : s[tid - 1]);
    if (idx < NV){
        rowptr[idx] = excl;
        cursor[idx] = excl;
    }
    if (idx == NV - 1) rowptr[NV] = NE;
}

__global__ void k_scatter(const int* __restrict__ dst, int* __restrict__ cursor,
                          int* __restrict__ csr_eid, int* __restrict__ csr_dst)
{
    int e = blockIdx.x*256 + threadIdx.x;
    if (e < NE){
        int i = dst[e];
        int p = atomicAdd(&cursor[i], 1);
        csr_eid[p] = e;
        csr_dst[p] = i;
    }
}

// ---------------- pack weights -> bf16 [l][{eWd,eWs,eW2,nW1d,nW1a,nW2}][n][k] ----------------
__global__ void k_pack_wpk(const float* __restrict__ ew1, const float* __restrict__ ew2,
                           const float* __restrict__ nw1, const float* __restrict__ nw2,
                           unsigned short* __restrict__ wpk)
{
    int idx = blockIdx.x*256 + threadIdx.x;
    int lm = idx >> 14;
    int l = lm / 6, m = lm % 6;
    int r = idx & 16383;
    int n = r >> 7, k = r & 127;
    float v;
    if (m < 2)       v = ew1[l*33152 + (m*128 + k)*128 + n];
    else if (m == 2) v = ew2[l*16384 + k*128 + n];
    else if (m < 5)  v = nw1[l*32768 + ((m-3)*128 + k)*128 + n];
    else             v = nw2[l*16384 + k*128 + n];
    wpk[idx] = f2bf(v);
}

// ---------------- pack W2 -> fp8 [l][n][k] ----------------
__global__ void k_pack_w2f8(const float* __restrict__ ew2, unsigned char* __restrict__ w2f8)
{
    int idx = blockIdx.x*256 + threadIdx.x;        // 4*16384
    int l = idx >> 14, r = idx & 16383;
    int n = r >> 7, k = r & 127;
    float v = ew2[l*16384 + k*128 + n];
    w2f8[idx] = (unsigned char)__builtin_amdgcn_cvt_pk_fp8_f32(v, v, 0, false);
}

// ---------------- layer-0 pre-projection (MFMA, merged branches; d->bf16, s->fp8; zeroes agg) ----------------
__global__ __launch_bounds__(256) void k_pre_mfma(
    const unsigned short* __restrict__ h, const float* __restrict__ xt,
    const unsigned short* __restrict__ wpk_l,   // Wd at +0, Ws at +16384
    const float* __restrict__ w1c, const float* __restrict__ b1,
    unsigned short* __restrict__ pre_di, unsigned char* __restrict__ pre_sj,
    float* __restrict__ agg)
{
    __shared__ __align__(16) unsigned short asd[64*SK];    // A tile; reused as d-out tile
    __shared__ __align__(16) unsigned short obuf[64*SK];   // s-out tile (bf16)
    __shared__ float xts[64*4];
    int tid = threadIdx.x;
    int tile0 = blockIdx.x*64;

    {
        int r = tid >> 2, dq = tid & 3;
        int node = tile0 + r;
        bool valid = node < NV;
        const uint4* hrow = (const uint4*)(h + (size_t)node*NH + dq*32);
        uint4 z4; z4.x = z4.y = z4.z = z4.w = 0u;
        #pragma unroll
        for (int c = 0; c < 4; c++){
            uint4 o = valid ? hrow[c] : z4;
            *(uint4*)&asd[r*SK + dq*32 + c*8] = o;
        }
        // zero agg rows for layer-0 edge pass
        if (valid){
            float4 zf = make_float4(0.f,0.f,0.f,0.f);
            float* ag = agg + (size_t)node*NH + dq*32;
            #pragma unroll
            for (int c = 0; c < 8; c++) *(float4*)(ag + c*4) = zf;
        }
    }
    if (tid < 64){
        int node = tile0 + tid;
        bool valid = node < NV;
        xts[tid*4+0] = valid ? xt[node*3+0] : 0.f;
        xts[tid*4+1] = valid ? xt[node*3+1] : 0.f;
        xts[tid*4+2] = valid ? xt[node*3+2] : 0.f;
        xts[tid*4+3] = 0.f;
    }

    int w = tid >> 6, l = tid & 63;
    int lr = l & 15, lq = l >> 4;

    short8 bfrd[2][4], bfrs[2][4];
    #pragma unroll
    for (int nt = 0; nt < 2; nt++)
        #pragma unroll
        for (int kc = 0; kc < 4; kc++){
            bfrd[nt][kc] = *(const short8*)(wpk_l +          (w*32 + nt*16 + lr)*128 + kc*32 + lq*8);
            bfrs[nt][kc] = *(const short8*)(wpk_l + 16384 +  (w*32 + nt*16 + lr)*128 + kc*32 + lq*8);
        }

    f32x4 accd[4][2], accs[4][2];
    #pragma unroll
    for (int mt = 0; mt < 4; mt++)
        #pragma unroll
        for (int nt = 0; nt < 2; nt++){
            accd[mt][nt] = (f32x4){0.f,0.f,0.f,0.f};
            accs[mt][nt] = (f32x4){0.f,0.f,0.f,0.f};
        }

    __syncthreads();

    #pragma unroll
    for (int kc = 0; kc < 4; kc++)
        #pragma unroll
        for (int mt = 0; mt < 4; mt++){
            short8 af = *(const short8*)&asd[(mt*16 + lr)*SK + kc*32 + lq*8];
            #pragma unroll
            for (int nt = 0; nt < 2; nt++){
                accd[mt][nt] = __builtin_amdgcn_mfma_f32_16x16x32_bf16(af, bfrd[nt][kc], accd[mt][nt], 0, 0, 0);
                accs[mt][nt] = __builtin_amdgcn_mfma_f32_16x16x32_bf16(af, bfrs[nt][kc], accs[mt][nt], 0, 0, 0);
            }
        }
    __syncthreads();

    #pragma unroll
    for (int nt = 0; nt < 2; nt++){
        int col = w*32 + nt*16 + lr;
        float c0 = w1c[col], c1 = w1c[128 + col], c2 = w1c[256 + col];
        float bb = b1[col];
        #pragma unroll
        for (int mt = 0; mt < 4; mt++){
            #pragma unroll
            for (int r = 0; r < 4; r++){
                int row = mt*16 + lq*4 + r;
                float qv = xts[row*4+0]*c0 + xts[row*4+1]*c1 + xts[row*4+2]*c2;
                asd [row*SK + col] = f2bf_fast(accd[mt][nt][r] + qv + bb);
                obuf[row*SK + col] = f2bf_fast(accs[mt][nt][r] - qv);
            }
        }
    }
    __syncthreads();

    {
        int r = tid >> 2, dq = tid & 3;
        int node = tile0 + r;
        if (node < NV){
            #pragma unroll
            for (int c = 0; c < 4; c++){
                uint4 vd = *(const uint4*)&asd[r*SK + dq*32 + c*8];
                *(uint4*)(pre_di + (size_t)node*NH + dq*32 + c*8) = vd;
            }
            bf16row_to_fp8(&obuf[r*SK + dq*32], pre_sj + (size_t)node*NH + dq*32);
        }
    }
}

// ---------------- fused edge kernel: 128-edge tiles; fp8; 2 col passes (32 AGPR) ----------------
// silu via direct 256-entry fp8->fp8 LDS LUT (broadcast-friendly; 2-way conflicts are free).
// m tile is held in registers across the MFMA passes and written into the SAME LDS region as
// the hid tile after a barrier -> LDS ~19 KB.
// Tuning history (keep this config): R8 min-waves 6 -> forced <=64-reg target -> spill
// (WRITE 31->202MB). R10 merged passes (64 acc regs, min-waves 4) -> occupancy 45.6->39.6%,
// dur 71->86us: kernel is latency-bound, wave count beats per-wave LDS-read savings.
__global__ __launch_bounds__(256, 5) void k_edge_mfma(
    const unsigned short* __restrict__ pre_di, const unsigned char* __restrict__ pre_sj,
    const int* __restrict__ csr_eid, const int* __restrict__ csr_dst,
    const int* __restrict__ srcrow, const int* __restrict__ rowptr,
    const unsigned char* __restrict__ w2f8,   // [n][k] fp8
    const float* __restrict__ b2,
    float* __restrict__ agg)
{
    __shared__ __align__(16) unsigned char hbuf[128*SKB];   // 17.4 KB: fp8 hid tile, then m tile
    __shared__ unsigned lutS[256];                          // fp8 code -> fp8(silu(decode(code)))
    __shared__ int nid[128];
    __shared__ int flagL, flagR;
    __shared__ unsigned long long brk0_s, brk1_s;
    int tid = threadIdx.x;
    unsigned char* hids8 = hbuf;       // [128][SKB] during MFMA passes
    unsigned char* m_t   = hbuf;       // [128][MTB] after the post-MFMA barrier

    int b = blockIdx.x;
    int mapped = (b < 6248) ? ((b & 7)*781 + (b >> 3)) : b;
    int p0 = mapped * 128;

    // build the silu LUT (one exact silu per thread, once per block)
    {
        f32x2 pv = __builtin_amdgcn_cvt_pk_f32_fp8((unsigned)tid, false);
        float y = silu_f(pv.x);
        lutS[tid] = __builtin_amdgcn_cvt_pk_fp8_f32(y, y, 0, false) & 0xffu;
    }

    if (tid == 0){
        flagL = (rowptr[csr_dst[p0]] < p0) ? 1 : 0;
        flagR = (rowptr[csr_dst[p0 + 127] + 1] > p0 + 128) ? 1 : 0;
    }
    __syncthreads();   // LUT visible before hid phase

    // hid phase: di bf16 + sj fp8 -> quantize fp8 -> LUT(silu) -> fp8 LDS
    #pragma unroll
    for (int sub = 0; sub < 2; sub++){
        int el = sub*64 + (tid >> 2), q = tid & 3;
        int p = p0 + el;
        int eid = csr_eid[p];
        int iN  = csr_dst[p];
        int jN  = srcrow[eid];
        if (q == 0) nid[el] = iN;
        const uint4* gd = (const uint4*)(pre_di + (size_t)iN*NH + q*32);
        const uint4* gs = (const uint4*)(pre_sj + (size_t)jN*NH + q*32);
        uint4 s0 = gs[0], s1 = gs[1];
        unsigned sw[8] = {s0.x, s0.y, s0.z, s0.w, s1.x, s1.y, s1.z, s1.w};
        #pragma unroll
        for (int c = 0; c < 4; c++){
            uint4 a = gd[c];
            f32x2 pa = __builtin_amdgcn_cvt_pk_f32_fp8(sw[c*2],   false);
            f32x2 pb = __builtin_amdgcn_cvt_pk_f32_fp8(sw[c*2],   true);
            f32x2 pc = __builtin_amdgcn_cvt_pk_f32_fp8(sw[c*2+1], false);
            f32x2 pd = __builtin_amdgcn_cvt_pk_f32_fp8(sw[c*2+1], true);
            float x0 = bflo(a.x) + pa.x;
            float x1 = bfhi(a.x) + pa.y;
            float x2 = bflo(a.y) + pb.x;
            float x3 = bfhi(a.y) + pb.y;
            float x4 = bflo(a.z) + pc.x;
            float x5 = bfhi(a.z) + pc.y;
            float x6 = bflo(a.w) + pd.x;
            float x7 = bfhi(a.w) + pd.y;
            unsigned q0 = __builtin_amdgcn_cvt_pk_fp8_f32(x0, x1, 0, false);
            q0 = __builtin_amdgcn_cvt_pk_fp8_f32(x2, x3, q0, true);
            unsigned q1 = __builtin_amdgcn_cvt_pk_fp8_f32(x4, x5, 0, false);
            q1 = __builtin_amdgcn_cvt_pk_fp8_f32(x6, x7, q1, true);
            unsigned w0 =  lutS[q0 & 0xff]
                        | (lutS[(q0 >> 8)  & 0xff] << 8)
                        | (lutS[(q0 >> 16) & 0xff] << 16)
                        | (lutS[ q0 >> 24        ] << 24);
            unsigned w1 =  lutS[q1 & 0xff]
                        | (lutS[(q1 >> 8)  & 0xff] << 8)
                        | (lutS[(q1 >> 16) & 0xff] << 16)
                        | (lutS[ q1 >> 24        ] << 24);
            uint2 o; o.x = w0; o.y = w1;
            *(uint2*)&hids8[el*SKB + q*32 + c*8] = o;
        }
    }

    int w = tid >> 6, l = tid & 63;
    int lr = l & 15, lq = l >> 4;
    // B frags for both col passes: pass p covers cols p*64 + w*16 + lr
    long bfr[2][4];
    #pragma unroll
    for (int pass = 0; pass < 2; pass++)
        #pragma unroll
        for (int kc = 0; kc < 4; kc++)
            bfr[pass][kc] = *(const long*)(w2f8 + (pass*64 + w*16 + lr)*128 + kc*32 + lq*8);

    __syncthreads();

    if (tid < 64){
        bool bb = (tid > 0) && (nid[tid] != nid[tid - 1]);
        unsigned long long mask = __ballot(bb);
        if (tid == 0) brk0_s = mask;
    } else if (tid < 128){
        int lane = tid - 64;
        bool bb = (nid[64 + lane] != nid[63 + lane]);
        unsigned long long mask = __ballot(bb);
        if (lane == 0) brk1_s = mask;
    }

    // two column passes, 32 AGPRs each; packed m results held in registers
    unsigned mreg[2][8];
    #pragma unroll
    for (int pass = 0; pass < 2; pass++){
        f32x4 acc[8];
        #pragma unroll
        for (int mt = 0; mt < 8; mt++) acc[mt] = (f32x4){0.f,0.f,0.f,0.f};
        #pragma unroll
        for (int kc = 0; kc < 4; kc++){
            #pragma unroll
            for (int mt = 0; mt < 8; mt++){
                long af = *(const long*)&hids8[(mt*16 + lr)*SKB + kc*32 + lq*8];
                acc[mt] = __builtin_amdgcn_mfma_f32_16x16x32_fp8_fp8(af, bfr[pass][kc], acc[mt], 0, 0, 0);
            }
        }
        int col = pass*64 + w*16 + lr;
        float bv = b2[col];
        #pragma unroll
        for (int mt = 0; mt < 8; mt++){
            unsigned qv = __builtin_amdgcn_cvt_pk_fp8_f32(acc[mt][0] + bv, acc[mt][1] + bv, 0, false);
            qv = __builtin_amdgcn_cvt_pk_fp8_f32(acc[mt][2] + bv, acc[mt][3] + bv, qv, true);
            mreg[pass][mt] =  lutS[qv & 0xff]
                           | (lutS[(qv >> 8)  & 0xff] << 8)
                           | (lutS[(qv >> 16) & 0xff] << 16)
                           | (lutS[ qv >> 24        ] << 24);
        }
    }
    __syncthreads();   // all hids8 reads complete -> region reusable as m tile

    #pragma unroll
    for (int pass = 0; pass < 2; pass++){
        int col = pass*64 + w*16 + lr;
        #pragma unroll
        for (int mt = 0; mt < 8; mt++)
            *(unsigned*)&m_t[col*MTB + mt*16 + lq*4] = mreg[pass][mt];
    }
    __syncthreads();

    {
        int half = tid >> 7, d = tid & 127;
        int r0 = half * 64;
        bool junc = !((brk1_s) & 1ull);
        unsigned long long m2 = half ? (brk1_s & ~1ull) : brk0_s;
        bool leftCont  = half ? junc : (flagL != 0);
        bool rightCont = half ? (flagR != 0) : junc;

        float run = 0.f;
        int curn = nid[r0];
        bool firstRun = true;
        const unsigned char* mrow = m_t + d*MTB;

        #pragma unroll
        for (int g = 0; g < 16; g++){
            int row = r0 + g*4;
            unsigned v = *(const unsigned*)&mrow[row];
            f32x2 pa = __builtin_amdgcn_cvt_pk_f32_fp8(v, false);
            f32x2 pb = __builtin_amdgcn_cvt_pk_f32_fp8(v, true);
            float f0 = pa.x, f1 = pa.y, f2 = pb.x, f3 = pb.y;
            unsigned gm = (unsigned)((m2 >> (g*4)) & 0xFull);
            if (gm == 0u){
                run += (f0 + f1) + (f2 + f3);
            } else {
                float fv[4] = {f0, f1, f2, f3};
                #pragma unroll
                for (int r = 0; r < 4; r++){
                    if (gm & (1u << r)){
                        bool at = firstRun && leftCont;
                        if (at) atomicAdd(&agg[(size_t)curn*NH + d], run);
                        else    agg[(size_t)curn*NH + d] = run;
                        firstRun = false;
                        run = 0.f;
                        curn = nid[row + r];
                    }
                    run += fv[r];
                }
            }
        }
        bool at = (firstRun && leftCont) || rightCont;
        if (at) atomicAdd(&agg[(size_t)curn*NH + d], run);
        else    agg[(size_t)curn*NH + d] = run;
    }
}

// ---------------- fused node kernel: LN(h + MLP([h|agg])) then next-layer pre; re-zeroes agg ----------------
// 32-node tiles (grid 1563): node kernel was grid-limited at 782 blocks (~3 blocks/CU).
// h is bf16 in global memory; residual comes from the a1 LDS tile (no mid-kernel h re-read).
__global__ __launch_bounds__(256) void k_node_fused(
    unsigned short* __restrict__ h, float* __restrict__ agg,
    const unsigned short* __restrict__ wn,   // node weights: W1d, W1a, W2
    const float* __restrict__ b1, const float* __restrict__ b2,
    const float* __restrict__ g, const float* __restrict__ bta,
    const float* __restrict__ xt,
    const unsigned short* __restrict__ wpk_next,   // next-layer eWd at +0, eWs at +16384
    const float* __restrict__ w1c_next, const float* __restrict__ b1_next,
    unsigned short* __restrict__ pre_di, unsigned char* __restrict__ pre_sj,
    int do_pre)
{
    __shared__ __align__(16) unsigned short abuf[2*32*SK];
    __shared__ float ps[32][8], pq[32][8];
    __shared__ float mu_s[32], rs_s[32];
    __shared__ float xts[32*4];
    int tid = threadIdx.x;
    int tile0 = blockIdx.x*32;
    unsigned short* a1 = abuf;            // holds bf16(h) until the LN phases complete
    unsigned short* a2 = abuf + 32*SK;    // agg -> silu(mlp1) -> mlp2+b2

    {
        int r = tid >> 3, t8 = tid & 7;   // 8 threads/row, 16 channels each
        int node = tile0 + r;
        bool valid = node < NV;
        const uint4*   hrow = (const uint4*)(h   + (size_t)node*NH + t8*16);
        const float4*  arow = (const float4*)(agg + (size_t)node*NH + t8*16);
        uint4 z4; z4.x = z4.y = z4.z = z4.w = 0u;
        #pragma unroll
        for (int c = 0; c < 2; c++){
            uint4 o = valid ? hrow[c] : z4;
            *(uint4*)&a1[r*SK + t8*16 + c*8] = o;
            float4 u0 = valid ? arow[c*2]     : make_float4(0.f,0.f,0.f,0.f);
            float4 u1 = valid ? arow[c*2 + 1] : make_float4(0.f,0.f,0.f,0.f);
            uint4 p;
            p.x = cvtpk(u0.x, u0.y); p.y = cvtpk(u0.z, u0.w);
            p.z = cvtpk(u1.x, u1.y); p.w = cvtpk(u1.z, u1.w);
            *(uint4*)&a2[r*SK + t8*16 + c*8] = p;
        }
        // re-zero agg for the next layer's edge pass (only if one follows)
        if (do_pre && valid){
            float4 zf = make_float4(0.f,0.f,0.f,0.f);
            float* ag = agg + (size_t)node*NH + t8*16;
            #pragma unroll
            for (int c = 0; c < 4; c++) *(float4*)(ag + c*4) = zf;
        }
    }
    if (tid < 32){
        int node = tile0 + tid;
        bool valid = node < NV;
        xts[tid*4+0] = valid ? xt[node*3+0] : 0.f;
        xts[tid*4+1] = valid ? xt[node*3+1] : 0.f;
        xts[tid*4+2] = valid ? xt[node*3+2] : 0.f;
        xts[tid*4+3] = 0.f;
    }

    int w = tid >> 6, l = tid & 63;
    int lr = l & 15, lq = l >> 4;
    int colb = w*32;

    __syncthreads();

    f32x4 acc[2][2];
    #pragma unroll
    for (int mt = 0; mt < 2; mt++)
        #pragma unroll
        for (int nt = 0; nt < 2; nt++) acc[mt][nt] = (f32x4){0.f,0.f,0.f,0.f};

    {
        short8 bfr[2][4];
        #pragma unroll
        for (int nt = 0; nt < 2; nt++)
            #pragma unroll
            for (int kc = 0; kc < 4; kc++)
                bfr[nt][kc] = *(const short8*)(wn + (colb + nt*16 + lr)*128 + kc*32 + lq*8);
        #pragma unroll
        for (int kc = 0; kc < 4; kc++)
            #pragma unroll
            for (int mt = 0; mt < 2; mt++){
                short8 af = *(const short8*)&a1[(mt*16 + lr)*SK + kc*32 + lq*8];
                #pragma unroll
                for (int nt = 0; nt < 2; nt++)
                    acc[mt][nt] = __builtin_amdgcn_mfma_f32_16x16x32_bf16(af, bfr[nt][kc], acc[mt][nt], 0, 0, 0);
            }
    }
    {
        short8 bfr[2][4];
        #pragma unroll
        for (int nt = 0; nt < 2; nt++)
            #pragma unroll
            for (int kc = 0; kc < 4; kc++)
                bfr[nt][kc] = *(const short8*)(wn + 16384 + (colb + nt*16 + lr)*128 + kc*32 + lq*8);
        #pragma unroll
        for (int kc = 0; kc < 4; kc++)
            #pragma unroll
            for (int mt = 0; mt < 2; mt++){
                short8 af = *(const short8*)&a2[(mt*16 + lr)*SK + kc*32 + lq*8];
                #pragma unroll
                for (int nt = 0; nt < 2; nt++)
                    acc[mt][nt] = __builtin_amdgcn_mfma_f32_16x16x32_bf16(af, bfr[nt][kc], acc[mt][nt], 0, 0, 0);
            }
    }
    __syncthreads();

    // silu(mlp1) -> a2 (keeps a1 = bf16(h) intact for the residual)
    #pragma unroll
    for (int nt = 0; nt < 2; nt++){
        int col = colb + nt*16 + lr;
        float bv = b1[col];
        #pragma unroll
        for (int mt = 0; mt < 2; mt++)
            #pragma unroll
            for (int r = 0; r < 4; r++){
                int row = mt*16 + lq*4 + r;
                a2[row*SK + col] = f2bf_fast(silu_f(acc[mt][nt][r] + bv));
            }
    }
    __syncthreads();

    f32x4 acc2[2][2];
    #pragma unroll
    for (int mt = 0; mt < 2; mt++)
        #pragma unroll
        for (int nt = 0; nt < 2; nt++) acc2[mt][nt] = (f32x4){0.f,0.f,0.f,0.f};
    {
        short8 bfr[2][4];
        #pragma unroll
        for (int nt = 0; nt < 2; nt++)
            #pragma unroll
            for (int kc = 0; kc < 4; kc++)
                bfr[nt][kc] = *(const short8*)(wn + 2*16384 + (colb + nt*16 + lr)*128 + kc*32 + lq*8);
        #pragma unroll
        for (int kc = 0; kc < 4; kc++)
            #pragma unroll
            for (int mt = 0; mt < 2; mt++){
                short8 af = *(const short8*)&a2[(mt*16 + lr)*SK + kc*32 + lq*8];
                #pragma unroll
                for (int nt = 0; nt < 2; nt++)
                    acc2[mt][nt] = __builtin_amdgcn_mfma_f32_16x16x32_bf16(af, bfr[nt][kc], acc2[mt][nt], 0, 0, 0);
            }
    }
    __syncthreads();

    // mlp2 + b2 -> a2 (bf16); residual x = a1 + a2 read in the LN phases
    #pragma unroll
    for (int nt = 0; nt < 2; nt++){
        int col = colb + nt*16 + lr;
        float bv = b2[col];
        #pragma unroll
        for (int mt = 0; mt < 2; mt++)
            #pragma unroll
            for (int r = 0; r < 4; r++){
                int row = mt*16 + lq*4 + r;
                a2[row*SK + col] = f2bf_fast(acc2[mt][nt][r] + bv);
            }
    }
    __syncthreads();

    {
        int r = tid >> 3, part = tid & 7;
        float s = 0.f, q = 0.f;
        #pragma unroll
        for (int c = 0; c < 2; c++){
            uint4 ua = *(const uint4*)&a1[r*SK + part*16 + c*8];
            uint4 ub = *(const uint4*)&a2[r*SK + part*16 + c*8];
            unsigned wa[4] = {ua.x, ua.y, ua.z, ua.w};
            unsigned wb[4] = {ub.x, ub.y, ub.z, ub.w};
            #pragma unroll
            for (int k = 0; k < 4; k++){
                float x0 = bflo(wa[k]) + bflo(wb[k]);
                float x1 = bfhi(wa[k]) + bfhi(wb[k]);
                s += x0 + x1;
                q += x0*x0 + x1*x1;
            }
        }
        ps[r][part] = s; pq[r][part] = q;
    }
    __syncthreads();
    if (tid < 32){
        float s = ps[tid][0] + ps[tid][1] + ps[tid][2] + ps[tid][3]
                + ps[tid][4] + ps[tid][5] + ps[tid][6] + ps[tid][7];
        float q = pq[tid][0] + pq[tid][1] + pq[tid][2] + pq[tid][3]
                + pq[tid][4] + pq[tid][5] + pq[tid][6] + pq[tid][7];
        float mu = s * (1.f/128.f);
        float var = q * (1.f/128.f) - mu*mu;
        mu_s[tid] = mu;
        rs_s[tid] = rsqrtf(var + 1e-5f);
    }
    __syncthreads();

    uint4 opk[2];   // LN output, bf16-packed (8 channels per uint4)
    {
        int r = tid >> 3, part = tid & 7;
        int node = tile0 + r;
        float mu = mu_s[r], rs = rs_s[r];
        #pragma unroll
        for (int c = 0; c < 2; c++){
            int d = part*16 + c*8;
            uint4 ua = *(const uint4*)&a1[r*SK + d];
            uint4 ub = *(const uint4*)&a2[r*SK + d];
            unsigned wa[4] = {ua.x, ua.y, ua.z, ua.w};
            unsigned wb[4] = {ub.x, ub.y, ub.z, ub.w};
            float xv[8];
            #pragma unroll
            for (int k = 0; k < 4; k++){
                xv[2*k]   = bflo(wa[k]) + bflo(wb[k]);
                xv[2*k+1] = bfhi(wa[k]) + bfhi(wb[k]);
            }
            float o0 = g[d+0]*(xv[0] - mu)*rs + bta[d+0];
            float o1 = g[d+1]*(xv[1] - mu)*rs + bta[d+1];
            float o2 = g[d+2]*(xv[2] - mu)*rs + bta[d+2];
            float o3 = g[d+3]*(xv[3] - mu)*rs + bta[d+3];
            float o4 = g[d+4]*(xv[4] - mu)*rs + bta[d+4];
            float o5 = g[d+5]*(xv[5] - mu)*rs + bta[d+5];
            float o6 = g[d+6]*(xv[6] - mu)*rs + bta[d+6];
            float o7 = g[d+7]*(xv[7] - mu)*rs + bta[d+7];
            uint4 po;
            po.x = cvtpk(o0, o1); po.y = cvtpk(o2, o3);
            po.z = cvtpk(o4, o5); po.w = cvtpk(o6, o7);
            opk[c] = po;
            if (node < NV) *(uint4*)(h + (size_t)node*NH + d) = po;
        }
    }

    if (!do_pre) return;

    __syncthreads();   // all a1/a2 LN reads done -> abuf reusable
    // pack LN result -> a1 (bf16 A-tile)
    {
        int r = tid >> 3, part = tid & 7;
        #pragma unroll
        for (int c = 0; c < 2; c++)
            *(uint4*)&a1[r*SK + part*16 + c*8] = opk[c];
    }

    // B frags for both branches
    short8 bfrd[2][4], bfrs[2][4];
    #pragma unroll
    for (int nt = 0; nt < 2; nt++)
        #pragma unroll
        for (int kc = 0; kc < 4; kc++){
            bfrd[nt][kc] = *(const short8*)(wpk_next +         (colb + nt*16 + lr)*128 + kc*32 + lq*8);
            bfrs[nt][kc] = *(const short8*)(wpk_next + 16384 + (colb + nt*16 + lr)*128 + kc*32 + lq*8);
        }

    f32x4 accd[2][2], accs[2][2];
    #pragma unroll
    for (int mt = 0; mt < 2; mt++)
        #pragma unroll
        for (int nt = 0; nt < 2; nt++){
            accd[mt][nt] = (f32x4){0.f,0.f,0.f,0.f};
            accs[mt][nt] = (f32x4){0.f,0.f,0.f,0.f};
        }

    __syncthreads();

    #pragma unroll
    for (int kc = 0; kc < 4; kc++)
        #pragma unroll
        for (int mt = 0; mt < 2; mt++){
            short8 af = *(const short8*)&a1[(mt*16 + lr)*SK + kc*32 + lq*8];
            #pragma unroll
            for (int nt = 0; nt < 2; nt++){
                accd[mt][nt] = __builtin_amdgcn_mfma_f32_16x16x32_bf16(af, bfrd[nt][kc], accd[mt][nt], 0, 0, 0);
                accs[mt][nt] = __builtin_amdgcn_mfma_f32_16x16x32_bf16(af, bfrs[nt][kc], accs[mt][nt], 0, 0, 0);
            }
        }

    // epilogue d -> a2
    #pragma unroll
    for (int nt = 0; nt < 2; nt++){
        int col = colb + nt*16 + lr;
        float c0 = w1c_next[col], c1 = w1c_next[128 + col], c2 = w1c_next[256 + col];
        float bb = b1_next[col];
        #pragma unroll
        for (int mt = 0; mt < 2; mt++)
            #pragma unroll
            for (int r = 0; r < 4; r++){
                int row = mt*16 + lq*4 + r;
                float qv = xts[row*4+0]*c0 + xts[row*4+1]*c1 + xts[row*4+2]*c2;
                a2[row*SK + col] = f2bf_fast(accd[mt][nt][r] + qv + bb);
            }
    }
    __syncthreads();   // d-tile visible; all a1 GEMM reads complete

    // store d from a2; epilogue s -> a1
    {
        int r = tid >> 3, t8 = tid & 7;
        int node = tile0 + r;
        if (node < NV){
            #pragma unroll
            for (int c = 0; c < 2; c++){
                uint4 vv = *(const uint4*)&a2[r*SK + t8*16 + c*8];
                *(uint4*)(pre_di + (size_t)node*NH + t8*16 + c*8) = vv;
            }
        }
    }
    #pragma unroll
    for (int nt = 0; nt < 2; nt++){
        int col = colb + nt*16 + lr;
        float c0 = w1c_next[col], c1 = w1c_next[128 + col], c2 = w1c_next[256 + col];
        #pragma unroll
        for (int mt = 0; mt < 2; mt++)
            #pragma unroll
            for (int r = 0; r < 4; r++){
                int row = mt*16 + lq*4 + r;
                float qv = xts[row*4+0]*c0 + xts[row*4+1]*c1 + xts[row*4+2]*c2;
                a1[row*SK + col] = f2bf_fast(accs[mt][nt][r] - qv);
            }
    }
    __syncthreads();

    // store s from a1 (fp8 convert)
    {
        int r = tid >> 3, t8 = tid & 7;
        int node = tile0 + r;
        if (node < NV){
            bf16row16_to_fp8(&a1[r*SK + t8*16], pre_sj + (size_t)node*NH + t8*16);
        }
    }
}

// ---------------- output projection + MSE (two-stage); h is bf16 ----------------
__global__ __launch_bounds__(256) void k_out(const unsigned short* __restrict__ h,
                                             const float* __restrict__ opw, const float* __restrict__ opb,
                                             const float* __restrict__ pos0, const float* __restrict__ pos1,
                                             float* __restrict__ partial)
{
    int v = blockIdx.x*256 + threadIdx.x;
    float sse = 0.f;
    if (v < NV){
        float v0 = opb[0], v1 = opb[1], v2 = opb[2];
        const unsigned short* hr = h + (size_t)v*NH;
        for (int k = 0; k < 128; k += 8){
            uint4 hv = *(const uint4*)(hr + k);
            unsigned u[4] = {hv.x, hv.y, hv.z, hv.w};
            #pragma unroll
            for (int j = 0; j < 4; j++){
                float f0 = bflo(u[j]), f1 = bfhi(u[j]);
                int kk = k + j*2;
                v0 += f0*opw[kk*3+0] + f1*opw[(kk+1)*3+0];
                v1 += f0*opw[kk*3+1] + f1*opw[(kk+1)*3+1];
                v2 += f0*opw[kk*3+2] + f1*opw[(kk+1)*3+2];
            }
        }
        float d0 = v0 - (pos1[v*3+0] - pos0[v*3+0]);
        float d1 = v1 - (pos1[v*3+1] - pos0[v*3+1]);
        float d2 = v2 - (pos1[v*3+2] - pos0[v*3+2]);
        sse = d0*d0 + d1*d1 + d2*d2;
    }
    for (int off = 32; off > 0; off >>= 1) sse += __shfl_down(sse, off, 64);
    __shared__ float red[4];
    if ((threadIdx.x & 63) == 0) red[threadIdx.x >> 6] = sse;
    __syncthreads();
    if (threadIdx.x == 0)
        partial[blockIdx.x] = red[0] + red[1] + red[2] + red[3];
}

__global__ void k_out2(const float* __restrict__ partial, float* __restrict__ out, int nparts)
{
    int tid = threadIdx.x;
    float s = (tid < nparts) ? partial[tid] : 0.f;
    for (int off = 32; off > 0; off >>= 1) s += __shfl_down(s, off, 64);
    __shared__ float red[4];
    if ((tid & 63) == 0) red[tid >> 6] = s;
    __syncthreads();
    if (tid == 0)
        out[0] = (red[0] + red[1] + red[2] + red[3]) * (1.0f/150000.0f);
}

extern "C" void kernel_launch(void* const* d_in, const int* in_sizes, int n_in,
                              void* d_out, int out_size, void* d_ws, size_t ws_size,
                              hipStream_t stream)
{
    const float* pos0  = (const float*)d_in[0];
    const float* pos1  = (const float*)d_in[1];
    const float* z     = (const float*)d_in[2];
    const float* t     = (const float*)d_in[3];
    const int*   ei    = (const int*)d_in[4];
    const int*   batch = (const int*)d_in[5];
    const float* te_w1 = (const float*)d_in[6];
    const float* te_b1 = (const float*)d_in[7];
    const float* te_w2 = (const float*)d_in[8];
    const float* te_b2 = (const float*)d_in[9];
    const float* cp_w  = (const float*)d_in[10];
    const float* cp_b  = (const float*)d_in[11];
    const float* ew1   = (const float*)d_in[12];
    const float* eb1   = (const float*)d_in[13];
    const float* ew2   = (const float*)d_in[14];
    const float* eb2   = (const float*)d_in[15];
    const float* nw1   = (const float*)d_in[16];
    const float* nb1   = (const float*)d_in[17];
    const float* nw2   = (const float*)d_in[18];
    const float* nb2   = (const float*)d_in[19];
    const float* ln_g  = (const float*)d_in[20];
    const float* ln_b  = (const float*)d_in[21];
    const float* op_w  = (const float*)d_in[22];
    const float* op_b  = (const float*)d_in[23];

    float* ws     = (float*)d_ws;
    float* tconst = ws;                        // 128
    float* zcp    = ws + 128;                  // 1024
    float* xt     = ws + 1152;                 // 150016 (NV*3 padded)
    unsigned short* h = (unsigned short*)(ws + 151168);   // NV*NH bf16 (in old fp32 slot)
    float* agg    = ws + 151168 + (size_t)NV*NH;          // NV*NH fp32 (same address as before)
    int*   ibase  = (int*)(agg + (size_t)NV*NH);
    int*   rowptr  = ibase;                    // 50016
    int*   cursor  = ibase + 50016;            // 50016
    int*   csr_eid = ibase + 100032;           // NE
    int*   csr_dst = csr_eid + NE;             // NE
    unsigned short* pre_di = (unsigned short*)(csr_dst + NE);   // NV*NH bf16
    unsigned char*  pre_sj = (unsigned char*)(pre_di + (size_t)NV*NH); // NV*NH fp8
    unsigned short* wpk    = (unsigned short*)(pre_sj + (size_t)NV*NH); // 4*6*16384 bf16
    int*   bsum   = (int*)(wpk + 4*6*16384);                    // 256 ints
    unsigned char* w2f8 = (unsigned char*)(bsum + 256);         // 4*16384 fp8
    float* outpart = (float*)(w2f8 + 4*16384);                  // 256 floats

    const int* srcrow = ei;        // edge_index[0] = src j
    const int* dstrow = ei + NE;   // edge_index[1] = dst i

    hipMemsetAsync(cursor, 0, (size_t)NV*4, stream);
    k_setup<<<1, 128, 0, stream>>>(z, t, te_w1, te_b1, te_w2, te_b2, cp_w, cp_b, tconst, zcp);
    k_init<<<(NV*64)/256, 256, 0, stream>>>(batch, zcp, tconst, h);
    k_xt<<<(NV*3 + 255)/256, 256, 0, stream>>>(pos0, pos1, t, xt);
    k_hist<<<NE/256, 256, 0, stream>>>(dstrow, cursor);
    k_scan1<<<196, 256, 0, stream>>>(cursor, bsum);
    k_scan2<<<1, 256, 0, stream>>>(bsum);
    k_scan3<<<196, 256, 0, stream>>>(cursor, bsum, rowptr, cursor);
    k_scatter<<<NE/256, 256, 0, stream>>>(dstrow, cursor, csr_eid, csr_dst);
    k_pack_wpk<<<(4*6*16384)/256, 256, 0, stream>>>(ew1, ew2, nw1, nw2, wpk);
    k_pack_w2f8<<<(4*16384)/256, 256, 0, stream>>>(ew2, w2f8);

    for (int l = 0; l < NL; l++){
        const unsigned short* wpk_l = wpk + (size_t)l*6*16384;
        if (l == 0){
            k_pre_mfma<<<(NV + 63)/64, 256, 0, stream>>>(h, xt, wpk_l,
                                                         ew1 + 256*128, eb1,
                                                         pre_di, pre_sj, agg);
        }
        k_edge_mfma<<<NE/128, 256, 0, stream>>>(pre_di, pre_sj, csr_eid, csr_dst, srcrow, rowptr,
                                                w2f8 + (size_t)l*16384, eb2 + l*128, agg);
        int ln = (l + 1) % NL;
        const unsigned short* wpk_n = wpk + (size_t)ln*6*16384;
        const float* ew1n = ew1 + (size_t)ln*259*128;
        k_node_fused<<<(NV + 31)/32, 256, 0, stream>>>(h, agg, wpk_l + 3*16384,
                                                       nb1 + l*128, nb2 + l*128,
                                                       ln_g + l*128, ln_b + l*128,
                                                       xt, wpk_n, ew1n + 256*128, eb1 + ln*128,
                                                       pre_di, pre_sj, (l < NL-1) ? 1 : 0);
    }

    int nparts = (NV + 255)/256;   // 196
    k_out<<<nparts, 256, 0, stream>>>(h, op_w, op_b, pos0, pos1, outpart);
    k_out2<<<1, 256, 0, stream>>>(outpart, (float*)d_out, nparts);
}

// Round 12
// 713.993 us; speedup vs baseline: 1.0382x; 1.0039x over previous
//
#include <hip/hip_runtime.h>

#define NV 50000
#define NE 800000
#define NB 8
#define NH 128
#define NLAT 64
#define NTD 16
#define NL 4
#define SK 136   // LDS row stride (bf16 elems) for MFMA A tiles
#define SKB 136  // LDS row stride (bytes) for fp8 hid tile in k_edge
#define MTB 132  // LDS stride (bytes) for transposed fp8 m tile

typedef __attribute__((ext_vector_type(8))) short short8;
typedef __attribute__((ext_vector_type(4))) float f32x4;
typedef __attribute__((ext_vector_type(2))) float f32x2;

__device__ __forceinline__ float silu_f(float x){
    float e = __expf(-x);
    return x * __builtin_amdgcn_rcpf(1.0f + e);
}

// HW packed f32->bf16 convert (RNE)
__device__ __forceinline__ unsigned cvtpk(float a, float b){
    unsigned r;
    asm("v_cvt_pk_bf16_f32 %0, %1, %2" : "=v"(r) : "v"(a), "v"(b));
    return r;
}
__device__ __forceinline__ unsigned short f2bf_fast(float x){
    return (unsigned short)cvtpk(x, x);
}
// bit-twiddle fallback for one-shot pack kernel
__device__ __forceinline__ unsigned short f2bf(float x){
    unsigned u = __float_as_uint(x);
    unsigned r = (u >> 16) & 1;
    u += 0x7fffu + r;
    return (unsigned short)(u >> 16);
}
__device__ __forceinline__ float bflo(unsigned u){ return __uint_as_float(u << 16); }
__device__ __forceinline__ float bfhi(unsigned u){ return __uint_as_float(u & 0xffff0000u); }

// 32 bf16 (LDS, 16B aligned) -> 32 fp8 bytes at dstg (global)
__device__ __forceinline__ void bf16row_to_fp8(const unsigned short* src, unsigned char* dstg){
    unsigned ow[8];
    #pragma unroll
    for (int c = 0; c < 8; c++){
        uint2 uu = *(const uint2*)(src + c*4);
        unsigned w = __builtin_amdgcn_cvt_pk_fp8_f32(bflo(uu.x), bfhi(uu.x), 0, false);
        w = __builtin_amdgcn_cvt_pk_fp8_f32(bflo(uu.y), bfhi(uu.y), w, true);
        ow[c] = w;
    }
    uint4 o0, o1;
    o0.x = ow[0]; o0.y = ow[1]; o0.z = ow[2]; o0.w = ow[3];
    o1.x = ow[4]; o1.y = ow[5]; o1.z = ow[6]; o1.w = ow[7];
    *(uint4*)(dstg)      = o0;
    *(uint4*)(dstg + 16) = o1;
}

// 16 bf16 (LDS, 16B aligned) -> 16 fp8 bytes at dstg (global)
__device__ __forceinline__ void bf16row16_to_fp8(const unsigned short* src, unsigned char* dstg){
    unsigned ow[4];
    #pragma unroll
    for (int c = 0; c < 4; c++){
        uint2 uu = *(const uint2*)(src + c*4);
        unsigned w = __builtin_amdgcn_cvt_pk_fp8_f32(bflo(uu.x), bfhi(uu.x), 0, false);
        w = __builtin_amdgcn_cvt_pk_fp8_f32(bflo(uu.y), bfhi(uu.y), w, true);
        ow[c] = w;
    }
    uint4 o0;
    o0.x = ow[0]; o0.y = ow[1]; o0.z = ow[2]; o0.w = ow[3];
    *(uint4*)(dstg) = o0;
}

// ---------------- setup ----------------
__global__ void k_setup(const float* __restrict__ z, const float* __restrict__ t,
                        const float* __restrict__ te_w1, const float* __restrict__ te_b1,
                        const float* __restrict__ te_w2, const float* __restrict__ te_b2,
                        const float* __restrict__ cp_w, const float* __restrict__ cp_b,
                        float* __restrict__ tconst, float* __restrict__ zcp)
{
    __shared__ float hid[NTD];
    __shared__ float emb[NTD];
    int tid = threadIdx.x;
    float ts = t[0];
    if (tid < NTD) hid[tid] = silu_f(ts * te_w1[tid] + te_b1[tid]);
    __syncthreads();
    if (tid < NTD){
        float a = te_b2[tid];
        for (int j = 0; j < NTD; j++) a += hid[j] * te_w2[j*NTD + tid];
        emb[tid] = a;
    }
    __syncthreads();
    float tc = cp_b[tid];
    for (int j = 0; j < NTD; j++) tc += emb[j] * cp_w[(NLAT + j)*NH + tid];
    tconst[tid] = tc;
    for (int b = 0; b < NB; b++){
        float a = 0.f;
        for (int k = 0; k < NLAT; k++) a += z[b*NLAT + k] * cp_w[k*NH + tid];
        zcp[b*NH + tid] = a;
    }
}

// h is stored bf16: one packed dword (2 channels) per thread
__global__ void k_init(const int* __restrict__ batch, const float* __restrict__ zcp,
                       const float* __restrict__ tconst, unsigned short* __restrict__ h)
{
    int pid = blockIdx.x*256 + threadIdx.x;      // NV*64 pairs
    int v = pid >> 6, d0 = (pid & 63) * 2;
    int b = batch[v];
    float x0 = zcp[b*NH + d0]     + tconst[d0];
    float x1 = zcp[b*NH + d0 + 1] + tconst[d0 + 1];
    ((unsigned*)h)[pid] = cvtpk(x0, x1);
}

__global__ void k_xt(const float* __restrict__ pos0, const float* __restrict__ pos1,
                     const float* __restrict__ t, float* __restrict__ xt)
{
    int idx = blockIdx.x*256 + threadIdx.x;
    if (idx < NV*3){
        float ts = t[0];
        xt[idx] = (1.f - ts)*pos0[idx] + ts*pos1[idx];
    }
}

// ---------------- CSR build ----------------
__global__ void k_hist(const int* __restrict__ dst, int* __restrict__ cnt)
{
    int e = blockIdx.x*256 + threadIdx.x;
    if (e < NE) atomicAdd(&cnt[dst[e]], 1);
}

__global__ void k_scan1(const int* __restrict__ deg, int* __restrict__ bsum)
{
    __shared__ int s[256];
    int tid = threadIdx.x;
    int idx = blockIdx.x*256 + tid;
    s[tid] = (idx < NV) ? deg[idx] : 0;
    __syncthreads();
    for (int off = 128; off > 0; off >>= 1){
        if (tid < off) s[tid] += s[tid + off];
        __syncthreads();
    }
    if (tid == 0) bsum[blockIdx.x] = s[0];
}

__global__ void k_scan2(int* __restrict__ bsum)
{
    __shared__ int s[256];
    int tid = threadIdx.x;
    int v = (tid < 196) ? bsum[tid] : 0;
    s[tid] = v;
    __syncthreads();
    for (int off = 1; off < 256; off <<= 1){
        int a = s[tid];
        int b = (tid >= off) ? s[tid - off] : 0;
        __syncthreads();
        s[tid] = a + b;
        __syncthreads();
    }
    if (tid < 196) bsum[tid] = (tid == 0) ? 0 : s[tid - 1];
}

__global__ void k_scan3(const int* deg, const int* __restrict__ bsum,
                        int* __restrict__ rowptr, int* cursor)
{
    __shared__ int s[256];
    int tid = threadIdx.x;
    int idx = blockIdx.x*256 + tid;
    int v = (idx < NV) ? deg[idx] : 0;
    s[tid] = v;
    __syncthreads();
    for (int off = 1; off < 256; off <<= 1){
        int a = s[tid];
        int b = (tid >= off) ? s[tid - off] : 0;
        __syncthreads();
        s[tid] = a + b;
        __syncthreads();
    }
    int excl = bsum[blockIdx.x] + ((tid == 0) ? 0 : s[tid - 1]);
    if (idx < NV){
        rowptr[idx] = excl;
        cursor[idx] = excl;
    }
    if (idx == NV - 1) rowptr[NV] = NE;
}

__global__ void k_scatter(const int* __restrict__ dst, int* __restrict__ cursor,
                          int* __restrict__ csr_eid, int* __restrict__ csr_dst)
{
    int e = blockIdx.x*256 + threadIdx.x;
    if (e < NE){
        int i = dst[e];
        int p = atomicAdd(&cursor[i], 1);
        csr_eid[p] = e;
        csr_dst[p] = i;
    }
}

// ---------------- pack weights -> bf16 [l][{eWd,eWs,eW2,nW1d,nW1a,nW2}][n][k] ----------------
__global__ void k_pack_wpk(const float* __restrict__ ew1, const float* __restrict__ ew2,
                           const float* __restrict__ nw1, const float* __restrict__ nw2,
                           unsigned short* __restrict__ wpk)
{
    int idx = blockIdx.x*256 + threadIdx.x;
    int lm = idx >> 14;
    int l = lm / 6, m = lm % 6;
    int r = idx & 16383;
    int n = r >> 7, k = r & 127;
    float v;
    if (m < 2)       v = ew1[l*33152 + (m*128 + k)*128 + n];
    else if (m == 2) v = ew2[l*16384 + k*128 + n];
    else if (m < 5)  v = nw1[l*32768 + ((m-3)*128 + k)*128 + n];
    else             v = nw2[l*16384 + k*128 + n];
    wpk[idx] = f2bf(v);
}

// ---------------- pack W2 -> fp8 [l][n][k] ----------------
__global__ void k_pack_w2f8(const float* __restrict__ ew2, unsigned char* __restrict__ w2f8)
{
    int idx = blockIdx.x*256 + threadIdx.x;        // 4*16384
    int l = idx >> 14, r = idx & 16383;
    int n = r >> 7, k = r & 127;
    float v = ew2[l*16384 + k*128 + n];
    w2f8[idx] = (unsigned char)__builtin_amdgcn_cvt_pk_fp8_f32(v, v, 0, false);
}

// ---------------- layer-0 pre-projection (MFMA, merged branches; d,s -> fp8; zeroes agg) ----------------
__global__ __launch_bounds__(256) void k_pre_mfma(
    const unsigned short* __restrict__ h, const float* __restrict__ xt,
    const unsigned short* __restrict__ wpk_l,   // Wd at +0, Ws at +16384
    const float* __restrict__ w1c, const float* __restrict__ b1,
    unsigned char* __restrict__ pre_d8, unsigned char* __restrict__ pre_sj,
    float* __restrict__ agg)
{
    __shared__ __align__(16) unsigned short asd[64*SK];    // A tile; reused as d-out tile
    __shared__ __align__(16) unsigned short obuf[64*SK];   // s-out tile (bf16)
    __shared__ float xts[64*4];
    int tid = threadIdx.x;
    int tile0 = blockIdx.x*64;

    {
        int r = tid >> 2, dq = tid & 3;
        int node = tile0 + r;
        bool valid = node < NV;
        const uint4* hrow = (const uint4*)(h + (size_t)node*NH + dq*32);
        uint4 z4; z4.x = z4.y = z4.z = z4.w = 0u;
        #pragma unroll
        for (int c = 0; c < 4; c++){
            uint4 o = valid ? hrow[c] : z4;
            *(uint4*)&asd[r*SK + dq*32 + c*8] = o;
        }
        // zero agg rows for layer-0 edge pass
        if (valid){
            float4 zf = make_float4(0.f,0.f,0.f,0.f);
            float* ag = agg + (size_t)node*NH + dq*32;
            #pragma unroll
            for (int c = 0; c < 8; c++) *(float4*)(ag + c*4) = zf;
        }
    }
    if (tid < 64){
        int node = tile0 + tid;
        bool valid = node < NV;
        xts[tid*4+0] = valid ? xt[node*3+0] : 0.f;
        xts[tid*4+1] = valid ? xt[node*3+1] : 0.f;
        xts[tid*4+2] = valid ? xt[node*3+2] : 0.f;
        xts[tid*4+3] = 0.f;
    }

    int w = tid >> 6, l = tid & 63;
    int lr = l & 15, lq = l >> 4;

    short8 bfrd[2][4], bfrs[2][4];
    #pragma unroll
    for (int nt = 0; nt < 2; nt++)
        #pragma unroll
        for (int kc = 0; kc < 4; kc++){
            bfrd[nt][kc] = *(const short8*)(wpk_l +          (w*32 + nt*16 + lr)*128 + kc*32 + lq*8);
            bfrs[nt][kc] = *(const short8*)(wpk_l + 16384 +  (w*32 + nt*16 + lr)*128 + kc*32 + lq*8);
        }

    f32x4 accd[4][2], accs[4][2];
    #pragma unroll
    for (int mt = 0; mt < 4; mt++)
        #pragma unroll
        for (int nt = 0; nt < 2; nt++){
            accd[mt][nt] = (f32x4){0.f,0.f,0.f,0.f};
            accs[mt][nt] = (f32x4){0.f,0.f,0.f,0.f};
        }

    __syncthreads();

    #pragma unroll
    for (int kc = 0; kc < 4; kc++)
        #pragma unroll
        for (int mt = 0; mt < 4; mt++){
            short8 af = *(const short8*)&asd[(mt*16 + lr)*SK + kc*32 + lq*8];
            #pragma unroll
            for (int nt = 0; nt < 2; nt++){
                accd[mt][nt] = __builtin_amdgcn_mfma_f32_16x16x32_bf16(af, bfrd[nt][kc], accd[mt][nt], 0, 0, 0);
                accs[mt][nt] = __builtin_amdgcn_mfma_f32_16x16x32_bf16(af, bfrs[nt][kc], accs[mt][nt], 0, 0, 0);
            }
        }
    __syncthreads();

    #pragma unroll
    for (int nt = 0; nt < 2; nt++){
        int col = w*32 + nt*16 + lr;
        float c0 = w1c[col], c1 = w1c[128 + col], c2 = w1c[256 + col];
        float bb = b1[col];
        #pragma unroll
        for (int mt = 0; mt < 4; mt++){
            #pragma unroll
            for (int r = 0; r < 4; r++){
                int row = mt*16 + lq*4 + r;
                float qv = xts[row*4+0]*c0 + xts[row*4+1]*c1 + xts[row*4+2]*c2;
                asd [row*SK + col] = f2bf_fast(accd[mt][nt][r] + qv + bb);
                obuf[row*SK + col] = f2bf_fast(accs[mt][nt][r] - qv);
            }
        }
    }
    __syncthreads();

    {
        int r = tid >> 2, dq = tid & 3;
        int node = tile0 + r;
        if (node < NV){
            bf16row_to_fp8(&asd [r*SK + dq*32], pre_d8 + (size_t)node*NH + dq*32);
            bf16row_to_fp8(&obuf[r*SK + dq*32], pre_sj + (size_t)node*NH + dq*32);
        }
    }
}

// ---------------- fused edge kernel: 128-edge tiles; fp8; 2 col passes (32 AGPR) ----------------
// silu via direct 256-entry fp8->fp8 LDS LUT (broadcast-friendly; 2-way conflicts are free).
// pre_d is fp8 (was bf16): halves the per-edge d-gather bytes; working set 19.2->12.8 MB.
// m tile is held in registers across the MFMA passes and written into the SAME LDS region as
// the hid tile after a barrier -> LDS ~19 KB.
// Tuning history (keep this config): R8 min-waves 6 -> spill; R10 merged passes -> occupancy
// loss; latency-bound, wave count beats per-wave LDS-read savings.
__global__ __launch_bounds__(256, 5) void k_edge_mfma(
    const unsigned char* __restrict__ pre_d8, const unsigned char* __restrict__ pre_sj,
    const int* __restrict__ csr_eid, const int* __restrict__ csr_dst,
    const int* __restrict__ srcrow, const int* __restrict__ rowptr,
    const unsigned char* __restrict__ w2f8,   // [n][k] fp8
    const float* __restrict__ b2,
    float* __restrict__ agg)
{
    __shared__ __align__(16) unsigned char hbuf[128*SKB];   // 17.4 KB: fp8 hid tile, then m tile
    __shared__ unsigned lutS[256];                          // fp8 code -> fp8(silu(decode(code)))
    __shared__ int nid[128];
    __shared__ int flagL, flagR;
    __shared__ unsigned long long brk0_s, brk1_s;
    int tid = threadIdx.x;
    unsigned char* hids8 = hbuf;       // [128][SKB] during MFMA passes
    unsigned char* m_t   = hbuf;       // [128][MTB] after the post-MFMA barrier

    int b = blockIdx.x;
    int mapped = (b < 6248) ? ((b & 7)*781 + (b >> 3)) : b;
    int p0 = mapped * 128;

    // build the silu LUT (one exact silu per thread, once per block)
    {
        f32x2 pv = __builtin_amdgcn_cvt_pk_f32_fp8((unsigned)tid, false);
        float y = silu_f(pv.x);
        lutS[tid] = __builtin_amdgcn_cvt_pk_fp8_f32(y, y, 0, false) & 0xffu;
    }

    if (tid == 0){
        flagL = (rowptr[csr_dst[p0]] < p0) ? 1 : 0;
        flagR = (rowptr[csr_dst[p0 + 127] + 1] > p0 + 128) ? 1 : 0;
    }
    __syncthreads();   // LUT visible before hid phase

    // hid phase: di fp8 + sj fp8 -> sum f32 -> quantize fp8 -> LUT(silu) -> fp8 LDS
    #pragma unroll
    for (int sub = 0; sub < 2; sub++){
        int el = sub*64 + (tid >> 2), q = tid & 3;
        int p = p0 + el;
        int eid = csr_eid[p];
        int iN  = csr_dst[p];
        int jN  = srcrow[eid];
        if (q == 0) nid[el] = iN;
        const uint4* gd = (const uint4*)(pre_d8 + (size_t)iN*NH + q*32);
        const uint4* gs = (const uint4*)(pre_sj + (size_t)jN*NH + q*32);
        uint4 d0 = gd[0], d1 = gd[1];
        uint4 s0 = gs[0], s1 = gs[1];
        unsigned dw[8] = {d0.x, d0.y, d0.z, d0.w, d1.x, d1.y, d1.z, d1.w};
        unsigned sw[8] = {s0.x, s0.y, s0.z, s0.w, s1.x, s1.y, s1.z, s1.w};
        #pragma unroll
        for (int c = 0; c < 4; c++){
            f32x2 da = __builtin_amdgcn_cvt_pk_f32_fp8(dw[c*2],   false);
            f32x2 db = __builtin_amdgcn_cvt_pk_f32_fp8(dw[c*2],   true);
            f32x2 dc = __builtin_amdgcn_cvt_pk_f32_fp8(dw[c*2+1], false);
            f32x2 de = __builtin_amdgcn_cvt_pk_f32_fp8(dw[c*2+1], true);
            f32x2 pa = __builtin_amdgcn_cvt_pk_f32_fp8(sw[c*2],   false);
            f32x2 pb = __builtin_amdgcn_cvt_pk_f32_fp8(sw[c*2],   true);
            f32x2 pc = __builtin_amdgcn_cvt_pk_f32_fp8(sw[c*2+1], false);
            f32x2 pd = __builtin_amdgcn_cvt_pk_f32_fp8(sw[c*2+1], true);
            float x0 = da.x + pa.x;
            float x1 = da.y + pa.y;
            float x2 = db.x + pb.x;
            float x3 = db.y + pb.y;
            float x4 = dc.x + pc.x;
            float x5 = dc.y + pc.y;
            float x6 = de.x + pd.x;
            float x7 = de.y + pd.y;
            unsigned q0 = __builtin_amdgcn_cvt_pk_fp8_f32(x0, x1, 0, false);
            q0 = __builtin_amdgcn_cvt_pk_fp8_f32(x2, x3, q0, true);
            unsigned q1 = __builtin_amdgcn_cvt_pk_fp8_f32(x4, x5, 0, false);
            q1 = __builtin_amdgcn_cvt_pk_fp8_f32(x6, x7, q1, true);
            unsigned w0 =  lutS[q0 & 0xff]
                        | (lutS[(q0 >> 8)  & 0xff] << 8)
                        | (lutS[(q0 >> 16) & 0xff] << 16)
                        | (lutS[ q0 >> 24        ] << 24);
            unsigned w1 =  lutS[q1 & 0xff]
                        | (lutS[(q1 >> 8)  & 0xff] << 8)
                        | (lutS[(q1 >> 16) & 0xff] << 16)
                        | (lutS[ q1 >> 24        ] << 24);
            uint2 o; o.x = w0; o.y = w1;
            *(uint2*)&hids8[el*SKB + q*32 + c*8] = o;
        }
    }

    int w = tid >> 6, l = tid & 63;
    int lr = l & 15, lq = l >> 4;
    // B frags for both col passes: pass p covers cols p*64 + w*16 + lr
    long bfr[2][4];
    #pragma unroll
    for (int pass = 0; pass < 2; pass++)
        #pragma unroll
        for (int kc = 0; kc < 4; kc++)
            bfr[pass][kc] = *(const long*)(w2f8 + (pass*64 + w*16 + lr)*128 + kc*32 + lq*8);

    __syncthreads();

    if (tid < 64){
        bool bb = (tid > 0) && (nid[tid] != nid[tid - 1]);
        unsigned long long mask = __ballot(bb);
        if (tid == 0) brk0_s = mask;
    } else if (tid < 128){
        int lane = tid - 64;
        bool bb = (nid[64 + lane] != nid[63 + lane]);
        unsigned long long mask = __ballot(bb);
        if (lane == 0) brk1_s = mask;
    }

    // two column passes, 32 AGPRs each; packed m results held in registers
    unsigned mreg[2][8];
    #pragma unroll
    for (int pass = 0; pass < 2; pass++){
        f32x4 acc[8];
        #pragma unroll
        for (int mt = 0; mt < 8; mt++) acc[mt] = (f32x4){0.f,0.f,0.f,0.f};
        #pragma unroll
        for (int kc = 0; kc < 4; kc++){
            #pragma unroll
            for (int mt = 0; mt < 8; mt++){
                long af = *(const long*)&hids8[(mt*16 + lr)*SKB + kc*32 + lq*8];
                acc[mt] = __builtin_amdgcn_mfma_f32_16x16x32_fp8_fp8(af, bfr[pass][kc], acc[mt], 0, 0, 0);
            }
        }
        int col = pass*64 + w*16 + lr;
        float bv = b2[col];
        #pragma unroll
        for (int mt = 0; mt < 8; mt++){
            unsigned qv = __builtin_amdgcn_cvt_pk_fp8_f32(acc[mt][0] + bv, acc[mt][1] + bv, 0, false);
            qv = __builtin_amdgcn_cvt_pk_fp8_f32(acc[mt][2] + bv, acc[mt][3] + bv, qv, true);
            mreg[pass][mt] =  lutS[qv & 0xff]
                           | (lutS[(qv >> 8)  & 0xff] << 8)
                           | (lutS[(qv >> 16) & 0xff] << 16)
                           | (lutS[ qv >> 24        ] << 24);
        }
    }
    __syncthreads();   // all hids8 reads complete -> region reusable as m tile

    #pragma unroll
    for (int pass = 0; pass < 2; pass++){
        int col = pass*64 + w*16 + lr;
        #pragma unroll
        for (int mt = 0; mt < 8; mt++)
            *(unsigned*)&m_t[col*MTB + mt*16 + lq*4] = mreg[pass][mt];
    }
    __syncthreads();

    {
        int half = tid >> 7, d = tid & 127;
        int r0 = half * 64;
        bool junc = !((brk1_s) & 1ull);
        unsigned long long m2 = half ? (brk1_s & ~1ull) : brk0_s;
        bool leftCont  = half ? junc : (flagL != 0);
        bool rightCont = half ? (flagR != 0) : junc;

        float run = 0.f;
        int curn = nid[r0];
        bool firstRun = true;
        const unsigned char* mrow = m_t + d*MTB;

        #pragma unroll
        for (int g = 0; g < 16; g++){
            int row = r0 + g*4;
            unsigned v = *(const unsigned*)&mrow[row];
            f32x2 pa = __builtin_amdgcn_cvt_pk_f32_fp8(v, false);
            f32x2 pb = __builtin_amdgcn_cvt_pk_f32_fp8(v, true);
            float f0 = pa.x, f1 = pa.y, f2 = pb.x, f3 = pb.y;
            unsigned gm = (unsigned)((m2 >> (g*4)) & 0xFull);
            if (gm == 0u){
                run += (f0 + f1) + (f2 + f3);
            } else {
                float fv[4] = {f0, f1, f2, f3};
                #pragma unroll
                for (int r = 0; r < 4; r++){
                    if (gm & (1u << r)){
                        bool at = firstRun && leftCont;
                        if (at) atomicAdd(&agg[(size_t)curn*NH + d], run);
                        else    agg[(size_t)curn*NH + d] = run;
                        firstRun = false;
                        run = 0.f;
                        curn = nid[row + r];
                    }
                    run += fv[r];
                }
            }
        }
        bool at = (firstRun && leftCont) || rightCont;
        if (at) atomicAdd(&agg[(size_t)curn*NH + d], run);
        else    agg[(size_t)curn*NH + d] = run;
    }
}

// ---------------- fused node kernel: LN(h + MLP([h|agg])) then next-layer pre; re-zeroes agg ----------------
// 32-node tiles (grid 1563): node kernel was grid-limited at 782 blocks (~3 blocks/CU).
// h is bf16 in global memory; residual comes from the a1 LDS tile (no mid-kernel h re-read).
// pre_d is written fp8 (symmetric with pre_s).
__global__ __launch_bounds__(256) void k_node_fused(
    unsigned short* __restrict__ h, float* __restrict__ agg,
    const unsigned short* __restrict__ wn,   // node weights: W1d, W1a, W2
    const float* __restrict__ b1, const float* __restrict__ b2,
    const float* __restrict__ g, const float* __restrict__ bta,
    const float* __restrict__ xt,
    const unsigned short* __restrict__ wpk_next,   // next-layer eWd at +0, eWs at +16384
    const float* __restrict__ w1c_next, const float* __restrict__ b1_next,
    unsigned char* __restrict__ pre_d8, unsigned char* __restrict__ pre_sj,
    int do_pre)
{
    __shared__ __align__(16) unsigned short abuf[2*32*SK];
    __shared__ float ps[32][8], pq[32][8];
    __shared__ float mu_s[32], rs_s[32];
    __shared__ float xts[32*4];
    int tid = threadIdx.x;
    int tile0 = blockIdx.x*32;
    unsigned short* a1 = abuf;            // holds bf16(h) until the LN phases complete
    unsigned short* a2 = abuf + 32*SK;    // agg -> silu(mlp1) -> mlp2+b2

    {
        int r = tid >> 3, t8 = tid & 7;   // 8 threads/row, 16 channels each
        int node = tile0 + r;
        bool valid = node < NV;
        const uint4*   hrow = (const uint4*)(h   + (size_t)node*NH + t8*16);
        const float4*  arow = (const float4*)(agg + (size_t)node*NH + t8*16);
        uint4 z4; z4.x = z4.y = z4.z = z4.w = 0u;
        #pragma unroll
        for (int c = 0; c < 2; c++){
            uint4 o = valid ? hrow[c] : z4;
            *(uint4*)&a1[r*SK + t8*16 + c*8] = o;
            float4 u0 = valid ? arow[c*2]     : make_float4(0.f,0.f,0.f,0.f);
            float4 u1 = valid ? arow[c*2 + 1] : make_float4(0.f,0.f,0.f,0.f);
            uint4 p;
            p.x = cvtpk(u0.x, u0.y); p.y = cvtpk(u0.z, u0.w);
            p.z = cvtpk(u1.x, u1.y); p.w = cvtpk(u1.z, u1.w);
            *(uint4*)&a2[r*SK + t8*16 + c*8] = p;
        }
        // re-zero agg for the next layer's edge pass (only if one follows)
        if (do_pre && valid){
            float4 zf = make_float4(0.f,0.f,0.f,0.f);
            float* ag = agg + (size_t)node*NH + t8*16;
            #pragma unroll
            for (int c = 0; c < 4; c++) *(float4*)(ag + c*4) = zf;
        }
    }
    if (tid < 32){
        int node = tile0 + tid;
        bool valid = node < NV;
        xts[tid*4+0] = valid ? xt[node*3+0] : 0.f;
        xts[tid*4+1] = valid ? xt[node*3+1] : 0.f;
        xts[tid*4+2] = valid ? xt[node*3+2] : 0.f;
        xts[tid*4+3] = 0.f;
    }

    int w = tid >> 6, l = tid & 63;
    int lr = l & 15, lq = l >> 4;
    int colb = w*32;

    __syncthreads();

    f32x4 acc[2][2];
    #pragma unroll
    for (int mt = 0; mt < 2; mt++)
        #pragma unroll
        for (int nt = 0; nt < 2; nt++) acc[mt][nt] = (f32x4){0.f,0.f,0.f,0.f};

    {
        short8 bfr[2][4];
        #pragma unroll
        for (int nt = 0; nt < 2; nt++)
            #pragma unroll
            for (int kc = 0; kc < 4; kc++)
                bfr[nt][kc] = *(const short8*)(wn + (colb + nt*16 + lr)*128 + kc*32 + lq*8);
        #pragma unroll
        for (int kc = 0; kc < 4; kc++)
            #pragma unroll
            for (int mt = 0; mt < 2; mt++){
                short8 af = *(const short8*)&a1[(mt*16 + lr)*SK + kc*32 + lq*8];
                #pragma unroll
                for (int nt = 0; nt < 2; nt++)
                    acc[mt][nt] = __builtin_amdgcn_mfma_f32_16x16x32_bf16(af, bfr[nt][kc], acc[mt][nt], 0, 0, 0);
            }
    }
    {
        short8 bfr[2][4];
        #pragma unroll
        for (int nt = 0; nt < 2; nt++)
            #pragma unroll
            for (int kc = 0; kc < 4; kc++)
                bfr[nt][kc] = *(const short8*)(wn + 16384 + (colb + nt*16 + lr)*128 + kc*32 + lq*8);
        #pragma unroll
        for (int kc = 0; kc < 4; kc++)
            #pragma unroll
            for (int mt = 0; mt < 2; mt++){
                short8 af = *(const short8*)&a2[(mt*16 + lr)*SK + kc*32 + lq*8];
                #pragma unroll
                for (int nt = 0; nt < 2; nt++)
                    acc[mt][nt] = __builtin_amdgcn_mfma_f32_16x16x32_bf16(af, bfr[nt][kc], acc[mt][nt], 0, 0, 0);
            }
    }
    __syncthreads();

    // silu(mlp1) -> a2 (keeps a1 = bf16(h) intact for the residual)
    #pragma unroll
    for (int nt = 0; nt < 2; nt++){
        int col = colb + nt*16 + lr;
        float bv = b1[col];
        #pragma unroll
        for (int mt = 0; mt < 2; mt++)
            #pragma unroll
            for (int r = 0; r < 4; r++){
                int row = mt*16 + lq*4 + r;
                a2[row*SK + col] = f2bf_fast(silu_f(acc[mt][nt][r] + bv));
            }
    }
    __syncthreads();

    f32x4 acc2[2][2];
    #pragma unroll
    for (int mt = 0; mt < 2; mt++)
        #pragma unroll
        for (int nt = 0; nt < 2; nt++) acc2[mt][nt] = (f32x4){0.f,0.f,0.f,0.f};
    {
        short8 bfr[2][4];
        #pragma unroll
        for (int nt = 0; nt < 2; nt++)
            #pragma unroll
            for (int kc = 0; kc < 4; kc++)
                bfr[nt][kc] = *(const short8*)(wn + 2*16384 + (colb + nt*16 + lr)*128 + kc*32 + lq*8);
        #pragma unroll
        for (int kc = 0; kc < 4; kc++)
            #pragma unroll
            for (int mt = 0; mt < 2; mt++){
                short8 af = *(const short8*)&a2[(mt*16 + lr)*SK + kc*32 + lq*8];
                #pragma unroll
                for (int nt = 0; nt < 2; nt++)
                    acc2[mt][nt] = __builtin_amdgcn_mfma_f32_16x16x32_bf16(af, bfr[nt][kc], acc2[mt][nt], 0, 0, 0);
            }
    }
    __syncthreads();

    // mlp2 + b2 -> a2 (bf16); residual x = a1 + a2 read in the LN phases
    #pragma unroll
    for (int nt = 0; nt < 2; nt++){
        int col = colb + nt*16 + lr;
        float bv = b2[col];
        #pragma unroll
        for (int mt = 0; mt < 2; mt++)
            #pragma unroll
            for (int r = 0; r < 4; r++){
                int row = mt*16 + lq*4 + r;
                a2[row*SK + col] = f2bf_fast(acc2[mt][nt][r] + bv);
            }
    }
    __syncthreads();

    {
        int r = tid >> 3, part = tid & 7;
        float s = 0.f, q = 0.f;
        #pragma unroll
        for (int c = 0; c < 2; c++){
            uint4 ua = *(const uint4*)&a1[r*SK + part*16 + c*8];
            uint4 ub = *(const uint4*)&a2[r*SK + part*16 + c*8];
            unsigned wa[4] = {ua.x, ua.y, ua.z, ua.w};
            unsigned wb[4] = {ub.x, ub.y, ub.z, ub.w};
            #pragma unroll
            for (int k = 0; k < 4; k++){
                float x0 = bflo(wa[k]) + bflo(wb[k]);
                float x1 = bfhi(wa[k]) + bfhi(wb[k]);
                s += x0 + x1;
                q += x0*x0 + x1*x1;
            }
        }
        ps[r][part] = s; pq[r][part] = q;
    }
    __syncthreads();
    if (tid < 32){
        float s = ps[tid][0] + ps[tid][1] + ps[tid][2] + ps[tid][3]
                + ps[tid][4] + ps[tid][5] + ps[tid][6] + ps[tid][7];
        float q = pq[tid][0] + pq[tid][1] + pq[tid][2] + pq[tid][3]
                + pq[tid][4] + pq[tid][5] + pq[tid][6] + pq[tid][7];
        float mu = s * (1.f/128.f);
        float var = q * (1.f/128.f) - mu*mu;
        mu_s[tid] = mu;
        rs_s[tid] = rsqrtf(var + 1e-5f);
    }
    __syncthreads();

    uint4 opk[2];   // LN output, bf16-packed (8 channels per uint4)
    {
        int r = tid >> 3, part = tid & 7;
        int node = tile0 + r;
        float mu = mu_s[r], rs = rs_s[r];
        #pragma unroll
        for (int c = 0; c < 2; c++){
            int d = part*16 + c*8;
            uint4 ua = *(const uint4*)&a1[r*SK + d];
            uint4 ub = *(const uint4*)&a2[r*SK + d];
            unsigned wa[4] = {ua.x, ua.y, ua.z, ua.w};
            unsigned wb[4] = {ub.x, ub.y, ub.z, ub.w};
            float xv[8];
            #pragma unroll
            for (int k = 0; k < 4; k++){
                xv[2*k]   = bflo(wa[k]) + bflo(wb[k]);
                xv[2*k+1] = bfhi(wa[k]) + bfhi(wb[k]);
            }
            float o0 = g[d+0]*(xv[0] - mu)*rs + bta[d+0];
            float o1 = g[d+1]*(xv[1] - mu)*rs + bta[d+1];
            float o2 = g[d+2]*(xv[2] - mu)*rs + bta[d+2];
            float o3 = g[d+3]*(xv[3] - mu)*rs + bta[d+3];
            float o4 = g[d+4]*(xv[4] - mu)*rs + bta[d+4];
            float o5 = g[d+5]*(xv[5] - mu)*rs + bta[d+5];
            float o6 = g[d+6]*(xv[6] - mu)*rs + bta[d+6];
            float o7 = g[d+7]*(xv[7] - mu)*rs + bta[d+7];
            uint4 po;
            po.x = cvtpk(o0, o1); po.y = cvtpk(o2, o3);
            po.z = cvtpk(o4, o5); po.w = cvtpk(o6, o7);
            opk[c] = po;
            if (node < NV) *(uint4*)(h + (size_t)node*NH + d) = po;
        }
    }

    if (!do_pre) return;

    __syncthreads();   // all a1/a2 LN reads done -> abuf reusable
    // pack LN result -> a1 (bf16 A-tile)
    {
        int r = tid >> 3, part = tid & 7;
        #pragma unroll
        for (int c = 0; c < 2; c++)
            *(uint4*)&a1[r*SK + part*16 + c*8] = opk[c];
    }

    // B frags for both branches
    short8 bfrd[2][4], bfrs[2][4];
    #pragma unroll
    for (int nt = 0; nt < 2; nt++)
        #pragma unroll
        for (int kc = 0; kc < 4; kc++){
            bfrd[nt][kc] = *(const short8*)(wpk_next +         (colb + nt*16 + lr)*128 + kc*32 + lq*8);
            bfrs[nt][kc] = *(const short8*)(wpk_next + 16384 + (colb + nt*16 + lr)*128 + kc*32 + lq*8);
        }

    f32x4 accd[2][2], accs[2][2];
    #pragma unroll
    for (int mt = 0; mt < 2; mt++)
        #pragma unroll
        for (int nt = 0; nt < 2; nt++){
            accd[mt][nt] = (f32x4){0.f,0.f,0.f,0.f};
            accs[mt][nt] = (f32x4){0.f,0.f,0.f,0.f};
        }

    __syncthreads();

    #pragma unroll
    for (int kc = 0; kc < 4; kc++)
        #pragma unroll
        for (int mt = 0; mt < 2; mt++){
            short8 af = *(const short8*)&a1[(mt*16 + lr)*SK + kc*32 + lq*8];
            #pragma unroll
            for (int nt = 0; nt < 2; nt++){
                accd[mt][nt] = __builtin_amdgcn_mfma_f32_16x16x32_bf16(af, bfrd[nt][kc], accd[mt][nt], 0, 0, 0);
                accs[mt][nt] = __builtin_amdgcn_mfma_f32_16x16x32_bf16(af, bfrs[nt][kc], accs[mt][nt], 0, 0, 0);
            }
        }

    // epilogue d -> a2
    #pragma unroll
    for (int nt = 0; nt < 2; nt++){
        int col = colb + nt*16 + lr;
        float c0 = w1c_next[col], c1 = w1c_next[128 + col], c2 = w1c_next[256 + col];
        float bb = b1_next[col];
        #pragma unroll
        for (int mt = 0; mt < 2; mt++)
            #pragma unroll
            for (int r = 0; r < 4; r++){
                int row = mt*16 + lq*4 + r;
                float qv = xts[row*4+0]*c0 + xts[row*4+1]*c1 + xts[row*4+2]*c2;
                a2[row*SK + col] = f2bf_fast(accd[mt][nt][r] + qv + bb);
            }
    }
    __syncthreads();   // d-tile visible; all a1 GEMM reads complete

    // store d (fp8) from a2; epilogue s -> a1
    {
        int r = tid >> 3, t8 = tid & 7;
        int node = tile0 + r;
        if (node < NV){
            bf16row16_to_fp8(&a2[r*SK + t8*16], pre_d8 + (size_t)node*NH + t8*16);
        }
    }
    #pragma unroll
    for (int nt = 0; nt < 2; nt++){
        int col = colb + nt*16 + lr;
        float c0 = w1c_next[col], c1 = w1c_next[128 + col], c2 = w1c_next[256 + col];
        #pragma unroll
        for (int mt = 0; mt < 2; mt++)
            #pragma unroll
            for (int r = 0; r < 4; r++){
                int row = mt*16 + lq*4 + r;
                float qv = xts[row*4+0]*c0 + xts[row*4+1]*c1 + xts[row*4+2]*c2;
                a1[row*SK + col] = f2bf_fast(accs[mt][nt][r] - qv);
            }
    }
    __syncthreads();

    // store s from a1 (fp8 convert)
    {
        int r = tid >> 3, t8 = tid & 7;
        int node = tile0 + r;
        if (node < NV){
            bf16row16_to_fp8(&a1[r*SK + t8*16], pre_sj + (size_t)node*NH + t8*16);
        }
    }
}

// ---------------- output projection + MSE (two-stage); h is bf16 ----------------
__global__ __launch_bounds__(256) void k_out(const unsigned short* __restrict__ h,
                                             const float* __restrict__ opw, const float* __restrict__ opb,
                                             const float* __restrict__ pos0, const float* __restrict__ pos1,
                                             float* __restrict__ partial)
{
    int v = blockIdx.x*256 + threadIdx.x;
    float sse = 0.f;
    if (v < NV){
        float v0 = opb[0], v1 = opb[1], v2 = opb[2];
        const unsigned short* hr = h + (size_t)v*NH;
        for (int k = 0; k < 128; k += 8){
            uint4 hv = *(const uint4*)(hr + k);
            unsigned u[4] = {hv.x, hv.y, hv.z, hv.w};
            #pragma unroll
            for (int j = 0; j < 4; j++){
                float f0 = bflo(u[j]), f1 = bfhi(u[j]);
                int kk = k + j*2;
                v0 += f0*opw[kk*3+0] + f1*opw[(kk+1)*3+0];
                v1 += f0*opw[kk*3+1] + f1*opw[(kk+1)*3+1];
                v2 += f0*opw[kk*3+2] + f1*opw[(kk+1)*3+2];
            }
        }
        float d0 = v0 - (pos1[v*3+0] - pos0[v*3+0]);
        float d1 = v1 - (pos1[v*3+1] - pos0[v*3+1]);
        float d2 = v2 - (pos1[v*3+2] - pos0[v*3+2]);
        sse = d0*d0 + d1*d1 + d2*d2;
    }
    for (int off = 32; off > 0; off >>= 1) sse += __shfl_down(sse, off, 64);
    __shared__ float red[4];
    if ((threadIdx.x & 63) == 0) red[threadIdx.x >> 6] = sse;
    __syncthreads();
    if (threadIdx.x == 0)
        partial[blockIdx.x] = red[0] + red[1] + red[2] + red[3];
}

__global__ void k_out2(const float* __restrict__ partial, float* __restrict__ out, int nparts)
{
    int tid = threadIdx.x;
    float s = (tid < nparts) ? partial[tid] : 0.f;
    for (int off = 32; off > 0; off >>= 1) s += __shfl_down(s, off, 64);
    __shared__ float red[4];
    if ((tid & 63) == 0) red[tid >> 6] = s;
    __syncthreads();
    if (tid == 0)
        out[0] = (red[0] + red[1] + red[2] + red[3]) * (1.0f/150000.0f);
}

extern "C" void kernel_launch(void* const* d_in, const int* in_sizes, int n_in,
                              void* d_out, int out_size, void* d_ws, size_t ws_size,
                              hipStream_t stream)
{
    const float* pos0  = (const float*)d_in[0];
    const float* pos1  = (const float*)d_in[1];
    const float* z     = (const float*)d_in[2];
    const float* t     = (const float*)d_in[3];
    const int*   ei    = (const int*)d_in[4];
    const int*   batch = (const int*)d_in[5];
    const float* te_w1 = (const float*)d_in[6];
    const float* te_b1 = (const float*)d_in[7];
    const float* te_w2 = (const float*)d_in[8];
    const float* te_b2 = (const float*)d_in[9];
    const float* cp_w  = (const float*)d_in[10];
    const float* cp_b  = (const float*)d_in[11];
    const float* ew1   = (const float*)d_in[12];
    const float* eb1   = (const float*)d_in[13];
    const float* ew2   = (const float*)d_in[14];
    const float* eb2   = (const float*)d_in[15];
    const float* nw1   = (const float*)d_in[16];
    const float* nb1   = (const float*)d_in[17];
    const float* nw2   = (const float*)d_in[18];
    const float* nb2   = (const float*)d_in[19];
    const float* ln_g  = (const float*)d_in[20];
    const float* ln_b  = (const float*)d_in[21];
    const float* op_w  = (const float*)d_in[22];
    const float* op_b  = (const float*)d_in[23];

    float* ws     = (float*)d_ws;
    float* tconst = ws;                        // 128
    float* zcp    = ws + 128;                  // 1024
    float* xt     = ws + 1152;                 // 150016 (NV*3 padded)
    unsigned short* h = (unsigned short*)(ws + 151168);   // NV*NH bf16 (in old fp32 slot)
    float* agg    = ws + 151168 + (size_t)NV*NH;          // NV*NH fp32 (same address as before)
    int*   ibase  = (int*)(agg + (size_t)NV*NH);
    int*   rowptr  = ibase;                    // 50016
    int*   cursor  = ibase + 50016;            // 50016
    int*   csr_eid = ibase + 100032;           // NE
    int*   csr_dst = csr_eid + NE;             // NE
    unsigned char* pre_d8 = (unsigned char*)(csr_dst + NE);     // NV*NH fp8 (slot sized bf16; half used)
    unsigned char* pre_sj = pre_d8 + (size_t)NV*NH*2;           // NV*NH fp8
    unsigned short* wpk    = (unsigned short*)(pre_sj + (size_t)NV*NH); // 4*6*16384 bf16
    int*   bsum   = (int*)(wpk + 4*6*16384);                    // 256 ints
    unsigned char* w2f8 = (unsigned char*)(bsum + 256);         // 4*16384 fp8
    float* outpart = (float*)(w2f8 + 4*16384);                  // 256 floats

    const int* srcrow = ei;        // edge_index[0] = src j
    const int* dstrow = ei + NE;   // edge_index[1] = dst i

    hipMemsetAsync(cursor, 0, (size_t)NV*4, stream);
    k_setup<<<1, 128, 0, stream>>>(z, t, te_w1, te_b1, te_w2, te_b2, cp_w, cp_b, tconst, zcp);
    k_init<<<(NV*64)/256, 256, 0, stream>>>(batch, zcp, tconst, h);
    k_xt<<<(NV*3 + 255)/256, 256, 0, stream>>>(pos0, pos1, t, xt);
    k_hist<<<NE/256, 256, 0, stream>>>(dstrow, cursor);
    k_scan1<<<196, 256, 0, stream>>>(cursor, bsum);
    k_scan2<<<1, 256, 0, stream>>>(bsum);
    k_scan3<<<196, 256, 0, stream>>>(cursor, bsum, rowptr, cursor);
    k_scatter<<<NE/256, 256, 0, stream>>>(dstrow, cursor, csr_eid, csr_dst);
    k_pack_wpk<<<(4*6*16384)/256, 256, 0, stream>>>(ew1, ew2, nw1, nw2, wpk);
    k_pack_w2f8<<<(4*16384)/256, 256, 0, stream>>>(ew2, w2f8);

    for (int l = 0; l < NL; l++){
        const unsigned short* wpk_l = wpk + (size_t)l*6*16384;
        if (l == 0){
            k_pre_mfma<<<(NV + 63)/64, 256, 0, stream>>>(h, xt, wpk_l,
                                                         ew1 + 256*128, eb1,
                                                         pre_d8, pre_sj, agg);
        }
        k_edge_mfma<<<NE/128, 256, 0, stream>>>(pre_d8, pre_sj, csr_eid, csr_dst, srcrow, rowptr,
                                                w2f8 + (size_t)l*16384, eb2 + l*128, agg);
        int ln = (l + 1) % NL;
        const unsigned short* wpk_n = wpk + (size_t)ln*6*16384;
        const float* ew1n = ew1 + (size_t)ln*259*128;
        k_node_fused<<<(NV + 31)/32, 256, 0, stream>>>(h, agg, wpk_l + 3*16384,
                                                       nb1 + l*128, nb2 + l*128,
                                                       ln_g + l*128, ln_b + l*128,
                                                       xt, wpk_n, ew1n + 256*128, eb1 + ln*128,
                                                       pre_d8, pre_sj, (l < NL-1) ? 1 : 0);
    }

    int nparts = (NV + 255)/256;   // 196
    k_out<<<nparts, 256, 0, stream>>>(h, op_w, op_b, pos0, pos1, outpart);
    k_out2<<<1, 256, 0, stream>>>(outpart, (float*)d_out, nparts);
}